// Round 3
// baseline (802.054 us; speedup 1.0000x reference)
//
#include <hip/hip_runtime.h>
#include <hip/hip_bf16.h>
#include <hip/hip_fp16.h>

#define N_NODES 10000
#define N_EDGES 640000
#define HID     128
#define NEG_SLOPE 0.2f
#define N_ACT   4096

// ---- persistent-kernel decomposition ----
#define GRID_MAX 400          // max blocks; actual nb = min(GRID_MAX, resident capacity)
#define EPT   7               // part1 edges/thread
#define EPB   1792            // 256*EPT
#define P1B   358             // ceil(N_EDGES/EPB)
#define NBKT  87              // buckets (part2 blocks)
#define NPB   115             // nodes per bucket (87*115 >= 10000)
#define SLOTP 64              // per (p1-tile, bucket) run capacity: mean 20.6, +9.6 sigma
#define GEMM_B 313            // gemm0 tiles (32 rows each)
#define FUSE_T 400            // fuse tiles (25 nodes each) = 10000 exactly
#define NPT   25
#define SC_T  256             // score tiles
#define SC_APB 16
#define EBUF_CAP 8192         // per-bucket edge cap: mean 7360, +9.7 sigma

// -------- device-scope grid barrier (all blocks resident by construction) --------
__device__ __forceinline__ void gsync(int* bar, int nb) {
    __syncthreads();
    if (threadIdx.x == 0) {
        int g = __hip_atomic_load(&bar[1], __ATOMIC_RELAXED, __HIP_MEMORY_SCOPE_AGENT);
        int n = __hip_atomic_fetch_add(&bar[0], 1, __ATOMIC_ACQ_REL, __HIP_MEMORY_SCOPE_AGENT);
        if (n == nb - 1) {
            __hip_atomic_store(&bar[0], 0, __ATOMIC_RELAXED, __HIP_MEMORY_SCOPE_AGENT);
            __hip_atomic_fetch_add(&bar[1], 1, __ATOMIC_ACQ_REL, __HIP_MEMORY_SCOPE_AGENT);
        } else {
            while (__hip_atomic_load(&bar[1], __ATOMIC_ACQUIRE, __HIP_MEMORY_SCOPE_AGENT) == g)
                __builtin_amdgcn_s_sleep(8);
        }
    }
    __syncthreads();
}

// inclusive 256-wide scan; sc stable after return
__device__ __forceinline__ int scan256(int* sc, int v, int t) {
    sc[t] = v;
    __syncthreads();
    for (int o = 1; o < 256; o <<= 1) {
        int u = (t >= o) ? sc[t - o] : 0;
        __syncthreads();
        sc[t] += u;
        __syncthreads();
    }
    return sc[t];
}

// -------- per-wave edge aggregate core: 2-deep pipelined row-load batches --------
__device__ __forceinline__ void agg_node(const __half2* __restrict__ z2,
                                         const float* __restrict__ zsi, float zdn,
                                         const int* __restrict__ csr, int o0, int deg,
                                         int lane, float& accx, float& accy, float& denom) {
    for (int base = 0; base < deg; base += 64) {
        int j = base + lane;
        int sreg = 0;
        float ex = 0.f;
        if (j < deg) {
            int s = csr[o0 + j];
            sreg = s;
            float e = zsi[s] + zdn;
            e = e > 0.f ? e : NEG_SLOPE * e;
            ex = __expf(e);
        }
        int cnt = min(64, deg - base);
        int nfull = cnt & ~7;
        int q = 0;
        if (nfull) {
            __half2 cur[8];
            float exc[8];
#pragma unroll
            for (int u = 0; u < 8; u++) {
                int sq = __builtin_amdgcn_readlane(sreg, u);
                exc[u] = __uint_as_float(__builtin_amdgcn_readlane(__float_as_uint(ex), u));
                cur[u] = z2[sq * 64];
            }
            for (q = 8; q < nfull; q += 8) {
                __half2 nxt[8];
                float exn[8];
#pragma unroll
                for (int u = 0; u < 8; u++) {
                    int sq = __builtin_amdgcn_readlane(sreg, q + u);
                    exn[u] = __uint_as_float(__builtin_amdgcn_readlane(__float_as_uint(ex), q + u));
                    nxt[u] = z2[sq * 64];
                }
#pragma unroll
                for (int u = 0; u < 8; u++) {
                    denom += exc[u];
                    float2 vf = __half22float2(cur[u]);
                    accx = fmaf(exc[u], vf.x, accx);
                    accy = fmaf(exc[u], vf.y, accy);
                    cur[u] = nxt[u];
                    exc[u] = exn[u];
                }
            }
#pragma unroll
            for (int u = 0; u < 8; u++) {
                denom += exc[u];
                float2 vf = __half22float2(cur[u]);
                accx = fmaf(exc[u], vf.x, accx);
                accy = fmaf(exc[u], vf.y, accy);
            }
            q = nfull;
        }
        for (; q < cnt; q++) {
            int sq = __builtin_amdgcn_readlane(sreg, q);
            float exq = __uint_as_float(__builtin_amdgcn_readlane(__float_as_uint(ex), q));
            denom += exq;
            float2 vf = __half22float2(z2[sq * 64]);
            accx = fmaf(exq, vf.x, accx);
            accy = fmaf(exq, vf.y, accy);
        }
    }
}

__device__ __forceinline__ void gload_lds16(const float* g, float* l) {
    __builtin_amdgcn_global_load_lds(
        (const __attribute__((address_space(1))) void*)g,
        (__attribute__((address_space(3))) void*)l, 16, 0, 0);
}

// ==================== the persistent mega-kernel ====================
__global__ __launch_bounds__(256, 2) void mega_k(
        const float* __restrict__ x, const int* __restrict__ ei,
        const int* __restrict__ asrc, const int* __restrict__ adst,
        const int* __restrict__ atype,
        const float* __restrict__ gW, const float* __restrict__ gas,
        const float* __restrict__ gad, const float* __restrict__ gb,
        const float* __restrict__ W1, const float* __restrict__ b1,
        const float* __restrict__ W2, const float* __restrict__ b2,
        float* __restrict__ out,
        __half* __restrict__ z16A, __half* __restrict__ z16B,
        float* __restrict__ h3,
        float* __restrict__ zsA, float* __restrict__ zdA,
        float* __restrict__ zsB, float* __restrict__ zdB,
        int* __restrict__ offs, int* __restrict__ csr,
        int* __restrict__ bcnt, unsigned* __restrict__ bpart,
        int* __restrict__ btot, int* __restrict__ bar, int nb) {
    __shared__ __align__(16) char smem8[81920];   // 80 KB -> 2 blocks/CU
    float* smemf = (float*)smem8;
    int t = threadIdx.x;
    int w = t >> 6, lane = t & 63;

    // ---------------- phase A: bucket counting-sort of real edges ----------------
    {
        int* hist = (int*)smem8;                  // 128 ints
        int* lofs = hist + 128;                   // 128 ints
        int* scA  = lofs + 128;                   // 256 ints
        unsigned* stage = (unsigned*)(scA + 256); // EPB
        unsigned char* bkt = (unsigned char*)(stage + EPB);

        for (int tile = blockIdx.x; tile < P1B; tile += nb) {
            int e0 = tile * EPB;
            if (t < 128) hist[t] = 0;
            __syncthreads();
            unsigned pk[EPT];
            int bk[EPT];
#pragma unroll
            for (int i = 0; i < EPT; i++) {
                int e = e0 + i * 256 + t;
                if (e < N_EDGES) {
                    int src = ei[e], dst = ei[N_EDGES + e];
                    pk[i] = ((unsigned)dst << 16) | (unsigned)src;
                    bk[i] = dst / NPB;
                    atomicAdd(&hist[bk[i]], 1);
                } else bk[i] = -1;
            }
            __syncthreads();
            int v = (t < NBKT) ? hist[t] : 0;
            int inc = scan256(scA, v, t);
            lofs[t] = inc - v;
            if (t < NBKT) {
                bcnt[t * P1B + tile] = v;
                if (v) atomicAdd(&btot[t], v);
                hist[t] = 0;
            }
            __syncthreads();
#pragma unroll
            for (int i = 0; i < EPT; i++) {
                if (bk[i] >= 0) {
                    int p = atomicAdd(&hist[bk[i]], 1);
                    int slot = lofs[bk[i]] + p;
                    stage[slot] = pk[i];
                    bkt[slot] = (unsigned char)bk[i];
                }
            }
            __syncthreads();
            int nv = min(EPB, N_EDGES - e0);
            for (int s = t; s < nv; s += 256) {
                int b = bkt[s];
                bpart[(b * P1B + tile) * SLOTP + (s - lofs[b])] = stage[s];
            }
            __syncthreads();
        }
    }
    gsync(bar, nb);

    // ---------------- phase B: gemm0 (tiles<GEMM_B) || CSR finalize ----------------
    for (int v = blockIdx.x; v < GEMM_B + NBKT; v += nb) {
        if (v < GEMM_B) {
            float* As = smemf;            // 16 KB
            float* Ws = smemf + 4096;     // 64 KB
            int row0 = v * 32;
#pragma unroll
            for (int i = 0; i < 4; i++) {
                int chunk = w * 4 + i;
                long foff = (long)row0 * HID + chunk * 256;
                const float* g = ((foff + 256) <= (long)N_NODES * HID) ? (x + foff + lane * 4)
                                                                       : (x + lane * 4);
                gload_lds16(g, As + chunk * 256);
            }
#pragma unroll
            for (int i = 0; i < 16; i++) {
                int chunk = w * 16 + i;
                gload_lds16(gW + chunk * 256 + lane * 4, Ws + chunk * 256);
            }
            __syncthreads();

            int tx = t & 31, ty = t >> 5;
            int r0 = ty * 4;
            float acc[4][4] = {{0.f}};
#pragma unroll 4
            for (int k4 = 0; k4 < 32; k4++) {
                float ak[4][4];
#pragma unroll
                for (int r = 0; r < 4; r++) {
                    float4 a4 = *(const float4*)&As[(r0 + r) * HID + k4 * 4];
                    ak[r][0] = a4.x; ak[r][1] = a4.y; ak[r][2] = a4.z; ak[r][3] = a4.w;
                }
                const float* Wb = &Ws[k4 * 4 * HID + tx * 4];
#pragma unroll
                for (int kk = 0; kk < 4; kk++) {
                    float4 wv = *(const float4*)&Wb[kk * HID];
#pragma unroll
                    for (int r = 0; r < 4; r++) {
                        acc[r][0] = fmaf(ak[r][kk], wv.x, acc[r][0]);
                        acc[r][1] = fmaf(ak[r][kk], wv.y, acc[r][1]);
                        acc[r][2] = fmaf(ak[r][kk], wv.z, acc[r][2]);
                        acc[r][3] = fmaf(ak[r][kk], wv.w, acc[r][3]);
                    }
                }
            }
            float4 asv = *(const float4*)&gas[t % 32 * 4];
            float4 adv = *(const float4*)&gad[t % 32 * 4];
#pragma unroll
            for (int r = 0; r < 4; r++) {
                int row = row0 + r0 + r;
                if (row < N_NODES) {
                    *(__half2*)&z16A[row * HID + tx * 4]     = __floats2half2_rn(acc[r][0], acc[r][1]);
                    *(__half2*)&z16A[row * HID + tx * 4 + 2] = __floats2half2_rn(acc[r][2], acc[r][3]);
                }
                float ps = acc[r][0] * asv.x + acc[r][1] * asv.y + acc[r][2] * asv.z + acc[r][3] * asv.w;
                float pd = acc[r][0] * adv.x + acc[r][1] * adv.y + acc[r][2] * adv.z + acc[r][3] * adv.w;
#pragma unroll
                for (int o = 1; o < 32; o <<= 1) {
                    ps += __shfl_xor(ps, o, 64);
                    pd += __shfl_xor(pd, o, 64);
                }
                if (tx == 0 && row < N_NODES) { zsA[row] = ps; zdA[row] = pd; }
            }
            __syncthreads();
        } else {
            // -------- CSR finalize for bucket b (self-loops inserted analytically) --------
            int b = v - GEMM_B;
            unsigned* ebuf = (unsigned*)smem8;            // 32 KB
            int* pref = (int*)(smem8 + 32768);            // 360 ints
            int* sc   = (int*)(smem8 + 34304);            // 256 ints
            int* nh   = (int*)(smem8 + 35328);            // 128 ints
            int* shs  = (int*)(smem8 + 35840);            // scalars

            // bucket start offsets from btot prefix (+ self-loop counts)
            int bv = (t < NBKT) ? btot[t] : 0;
            int inc1 = scan256(sc, bv, t);
            if (t == b) shs[0] = (inc1 - bv) + NPB * b;
            if (b == 0 && t == NBKT - 1) offs[N_NODES] = inc1 + N_NODES;
            __syncthreads();

            // run-offset scan over the 358 p1-tiles (pairs)
            int L0 = 0, L1 = 0;
            if (t < P1B / 2) {
                L0 = bcnt[b * P1B + 2 * t];
                L1 = bcnt[b * P1B + 2 * t + 1];
            }
            int inc2 = scan256(sc, L0 + L1, t);
            if (t < P1B / 2) {
                pref[2 * t]     = inc2 - (L0 + L1);
                pref[2 * t + 1] = inc2 - (L0 + L1) + L0;
            }
            if (t == 255) pref[P1B] = sc[255];
            __syncthreads();
            int cnt = pref[P1B];
            if (cnt > EBUF_CAP) cnt = EBUF_CAP;           // replay-safety

            // cooperative gather (run length <= SLOTP = 64 = one wave pass)
            for (int r = w; r < P1B; r += 4) {
                int p0 = pref[r];
                int Lr = pref[r + 1] - p0;
                if (lane < Lr && (unsigned)(p0 + lane) < EBUF_CAP)
                    ebuf[p0 + lane] = bpart[(b * P1B + r) * SLOTP + lane];
            }
            __syncthreads();

            int npb = min(NPB, N_NODES - b * NPB);
            int n0 = b * NPB;
            if (t < 128) nh[t] = (t < npb) ? 1 : 0;       // self-loop pre-count
            __syncthreads();
            for (int i = t; i < cnt; i += 256)
                atomicAdd(&nh[((ebuf[i] >> 16) - n0) & 127], 1);
            __syncthreads();
            int dv = (t < 128) ? nh[t] : 0;
            int inc3 = scan256(sc, dv, t);
            int bstart = shs[0];
            if (t < npb) {
                int nofs = bstart + inc3 - dv;
                offs[n0 + t] = nofs;
                if ((unsigned)nofs < (unsigned)(N_EDGES + N_NODES)) csr[nofs] = n0 + t;  // self
                nh[t] = nofs + 1;
            }
            __syncthreads();
            for (int i = t; i < cnt; i += 256) {
                unsigned pk = ebuf[i];
                int d = ((pk >> 16) - n0) & 127;
                int p = atomicAdd(&nh[d], 1);
                if ((unsigned)p < (unsigned)(N_EDGES + N_NODES)) csr[p] = pk & 0xFFFF;
            }
            __syncthreads();
        }
    }
    gsync(bar, nb);

    // ---------------- phases C/D/E: GAT layers ----------------
    for (int l = 0; l < 3; l++) {
        const __half* zin = (l == 1) ? z16B : z16A;
        const float* zsl  = (l == 1) ? zsB : zsA;
        const float* zdl  = (l == 1) ? zdB : zdA;
        __half* zout = (l == 0) ? z16B : z16A;
        float* zso   = (l == 0) ? zsB : zsA;
        float* zdo   = (l == 0) ? zdB : zdA;
        const float* bias = gb + l * HID;
        const __half2* z2 = (const __half2*)zin + lane;
        float2 bv2 = *(const float2*)&bias[2 * lane];

        if (l < 2) {
            const float* Wl   = gW + (l + 1) * HID * HID;
            const float* avsl = gas + (l + 1) * HID;
            const float* avdl = gad + (l + 1) * HID;
            float* hT = smemf;              // 25*128 floats = 12.8 KB
            float* Ws = smemf + 4096;       // 64 KB @ offset 16 KB

            for (int tile = blockIdx.x; tile < FUSE_T; tile += nb) {
                int n0 = tile * NPT;
                // one-shot W stage; loads fly during the whole agg phase
#pragma unroll
                for (int i = 0; i < 16; i++) {
                    int chunk = w * 16 + i;
                    gload_lds16(Wl + chunk * 256 + lane * 4, Ws + chunk * 256);
                }
                for (int ln = w; ln < NPT; ln += 4) {
                    int n = n0 + ln;
                    int o0 = offs[n];
                    int deg = offs[n + 1] - o0;
                    if (deg < 0) deg = 0;
                    if (deg > 2048) deg = 2048;           // replay-safety
                    float zdn = zdl[n];
                    float accx = 0.f, accy = 0.f, denom = 0.f;
                    agg_node(z2, zsl, zdn, csr, o0, deg, lane, accx, accy, denom);
                    float inv = 1.0f / denom;
                    float vx = accx * inv + bv2.x;
                    float vy = accy * inv + bv2.y;
                    float2 hv;
                    hv.x = vx > 0.f ? vx : 0.f;
                    hv.y = vy > 0.f ? vy : 0.f;
                    *(float2*)&hT[ln * HID + 2 * lane] = hv;
                }
                __syncthreads();
                // gemm: 25 x 128 x 128 from LDS
                int tx = t & 31, ty = t >> 5;
                float acc[4][4] = {{0.f}};
#pragma unroll 4
                for (int k4 = 0; k4 < 32; k4++) {
                    float4 av[4];
#pragma unroll
                    for (int u = 0; u < 4; u++) {
                        int r = ty + 8 * u;
                        int rr = (r < NPT) ? r : 0;
                        av[u] = *(const float4*)&hT[rr * HID + k4 * 4];
                    }
#pragma unroll
                    for (int kk = 0; kk < 4; kk++) {
                        float4 wv = *(const float4*)&Ws[(k4 * 4 + kk) * HID + tx * 4];
#pragma unroll
                        for (int u = 0; u < 4; u++) {
                            float f = (kk == 0) ? av[u].x : (kk == 1) ? av[u].y
                                     : (kk == 2) ? av[u].z : av[u].w;
                            acc[u][0] = fmaf(f, wv.x, acc[u][0]);
                            acc[u][1] = fmaf(f, wv.y, acc[u][1]);
                            acc[u][2] = fmaf(f, wv.z, acc[u][2]);
                            acc[u][3] = fmaf(f, wv.w, acc[u][3]);
                        }
                    }
                }
                float4 asv = *(const float4*)&avsl[tx * 4];
                float4 adv = *(const float4*)&avdl[tx * 4];
#pragma unroll
                for (int u = 0; u < 4; u++) {
                    int r = ty + 8 * u;
                    int row = n0 + r;
                    float ps = acc[u][0] * asv.x + acc[u][1] * asv.y + acc[u][2] * asv.z + acc[u][3] * asv.w;
                    float pd = acc[u][0] * adv.x + acc[u][1] * adv.y + acc[u][2] * adv.z + acc[u][3] * adv.w;
#pragma unroll
                    for (int o = 1; o < 32; o <<= 1) {
                        ps += __shfl_xor(ps, o, 64);
                        pd += __shfl_xor(pd, o, 64);
                    }
                    if (r < NPT) {
                        *(__half2*)&zout[row * HID + tx * 4]     = __floats2half2_rn(acc[u][0], acc[u][1]);
                        *(__half2*)&zout[row * HID + tx * 4 + 2] = __floats2half2_rn(acc[u][2], acc[u][3]);
                        if (tx == 0) { zso[row] = ps; zdo[row] = pd; }
                    }
                }
                __syncthreads();
            }
        } else {
            // final aggregate -> h3 (f32)
            for (int tile = blockIdx.x; tile < FUSE_T; tile += nb) {
                int n0 = tile * NPT;
                for (int ln = w; ln < NPT; ln += 4) {
                    int n = n0 + ln;
                    int o0 = offs[n];
                    int deg = offs[n + 1] - o0;
                    if (deg < 0) deg = 0;
                    if (deg > 2048) deg = 2048;
                    float zdn = zdl[n];
                    float accx = 0.f, accy = 0.f, denom = 0.f;
                    agg_node(z2, zsl, zdn, csr, o0, deg, lane, accx, accy, denom);
                    float inv = 1.0f / denom;
                    float vx = accx * inv + bv2.x;
                    float vy = accy * inv + bv2.y;
                    float2 o;
                    o.x = vx > 0.f ? vx : 0.f;
                    o.y = vy > 0.f ? vy : 0.f;
                    *(float2*)&h3[n * HID + 2 * lane] = o;
                }
            }
        }
        gsync(bar, nb);
    }

    // ---------------- phase F: action scoring ----------------
    {
        float* featT = smemf;                      // [257][17] floats
        float* Wc0 = (float*)(smem8 + 17920);      // dbuf 2 x 4096 floats
        for (int tile = blockIdx.x; tile < SC_T; tile += nb) {
            int a0 = tile * SC_APB;
            float4 wreg[4];
            {
                const float4* Wg = (const float4*)W1;
#pragma unroll
                for (int i = 0; i < 4; i++) wreg[i] = Wg[t + 256 * i];
            }
            for (int idx = t; idx < SC_APB * 128; idx += 256) {
                int a = idx >> 7, c = idx & 127;
                featT[c * 17 + a]         = h3[asrc[a0 + a] * HID + c];
                featT[(128 + c) * 17 + a] = h3[adst[a0 + a] * HID + c];
            }
            if (t < SC_APB) featT[256 * 17 + t] = (float)atype[a0 + t];

            int cg = t & 31, ap = t >> 5;
            float4 bv = *(const float4*)&b1[cg * 4];
            float acc0[4] = {bv.x, bv.y, bv.z, bv.w};
            float acc1[4] = {bv.x, bv.y, bv.z, bv.w};

            for (int c = 0; c < 8; c++) {
                float4* dstb = (float4*)(Wc0 + (c & 1) * 4096);
#pragma unroll
                for (int i = 0; i < 4; i++) dstb[t + 256 * i] = wreg[i];
                __syncthreads();
                if (c + 1 < 8) {
                    const float4* Wg = (const float4*)(W1 + (c + 1) * 32 * HID);
#pragma unroll
                    for (int i = 0; i < 4; i++) wreg[i] = Wg[t + 256 * i];
                }
                const float* Wb = Wc0 + (c & 1) * 4096;
                const float* fT = &featT[(c * 32) * 17];
#pragma unroll 8
                for (int kk = 0; kk < 32; kk++) {
                    float4 wv = *(const float4*)&Wb[kk * HID + cg * 4];
                    float f0 = fT[kk * 17 + ap * 2];
                    float f1 = fT[kk * 17 + ap * 2 + 1];
                    acc0[0] = fmaf(f0, wv.x, acc0[0]);
                    acc0[1] = fmaf(f0, wv.y, acc0[1]);
                    acc0[2] = fmaf(f0, wv.z, acc0[2]);
                    acc0[3] = fmaf(f0, wv.w, acc0[3]);
                    acc1[0] = fmaf(f1, wv.x, acc1[0]);
                    acc1[1] = fmaf(f1, wv.y, acc1[1]);
                    acc1[2] = fmaf(f1, wv.z, acc1[2]);
                    acc1[3] = fmaf(f1, wv.w, acc1[3]);
                }
                __syncthreads();
            }
            {
                float4 wv = *(const float4*)&W1[256 * HID + cg * 4];
                float f0 = featT[256 * 17 + ap * 2];
                float f1 = featT[256 * 17 + ap * 2 + 1];
                acc0[0] = fmaf(f0, wv.x, acc0[0]); acc0[1] = fmaf(f0, wv.y, acc0[1]);
                acc0[2] = fmaf(f0, wv.z, acc0[2]); acc0[3] = fmaf(f0, wv.w, acc0[3]);
                acc1[0] = fmaf(f1, wv.x, acc1[0]); acc1[1] = fmaf(f1, wv.y, acc1[1]);
                acc1[2] = fmaf(f1, wv.z, acc1[2]); acc1[3] = fmaf(f1, wv.w, acc1[3]);
            }
            float4 w2v = *(const float4*)&W2[cg * 4];
            float v0 = 0.f, v1 = 0.f;
            v0 += (acc0[0] > 0.f ? acc0[0] : 0.f) * w2v.x;
            v0 += (acc0[1] > 0.f ? acc0[1] : 0.f) * w2v.y;
            v0 += (acc0[2] > 0.f ? acc0[2] : 0.f) * w2v.z;
            v0 += (acc0[3] > 0.f ? acc0[3] : 0.f) * w2v.w;
            v1 += (acc1[0] > 0.f ? acc1[0] : 0.f) * w2v.x;
            v1 += (acc1[1] > 0.f ? acc1[1] : 0.f) * w2v.y;
            v1 += (acc1[2] > 0.f ? acc1[2] : 0.f) * w2v.z;
            v1 += (acc1[3] > 0.f ? acc1[3] : 0.f) * w2v.w;
#pragma unroll
            for (int o = 1; o < 32; o <<= 1) {
                v0 += __shfl_xor(v0, o, 64);
                v1 += __shfl_xor(v1, o, 64);
            }
            if (cg == 0) {
                out[a0 + ap * 2]     = v0 + b2[0];
                out[a0 + ap * 2 + 1] = v1 + b2[0];
            }
            __syncthreads();
        }
    }
}

// ---------------- launch ----------------

extern "C" void kernel_launch(void* const* d_in, const int* in_sizes, int n_in,
                              void* d_out, int out_size, void* d_ws, size_t ws_size,
                              hipStream_t stream) {
    const float* x   = (const float*)d_in[0];
    const int* ei    = (const int*)d_in[1];
    const int* asrc  = (const int*)d_in[2];
    const int* adst  = (const int*)d_in[3];
    const int* atype = (const int*)d_in[4];
    const float* gW  = (const float*)d_in[5];
    const float* gas = (const float*)d_in[6];
    const float* gad = (const float*)d_in[7];
    const float* gb  = (const float*)d_in[8];
    const float* W1  = (const float*)d_in[9];
    const float* b1  = (const float*)d_in[10];
    const float* W2  = (const float*)d_in[11];
    const float* b2  = (const float*)d_in[12];
    float* out = (float*)d_out;

    char* p = (char*)d_ws;
    __half* z16A = (__half*)p;            p += 2560000;
    __half* z16B = (__half*)p;            p += 2560000;
    float* h3   = (float*)p;              p += 5120000;
    float* zsA  = (float*)p;              p += 40000;
    float* zdA  = (float*)p;              p += 40000;
    float* zsB  = (float*)p;              p += 40000;
    float* zdB  = (float*)p;              p += 40000;
    int* offs   = (int*)p;                p += 40064;
    int* csr    = (int*)p;                p += 2600000;
    int* bcnt   = (int*)p;                p += 124608;            // NBKT*P1B ints
    unsigned* bpart = (unsigned*)p;       p += (size_t)NBKT * P1B * SLOTP * 4;
    int* btot   = (int*)p;                                         // 87 ints
    int* bar    = btot + 112;                                      // cnt, gen

    static int nb_cache = 0;
    if (nb_cache == 0) {
        int bpc = 1, ncu = 256;
        hipOccupancyMaxActiveBlocksPerMultiprocessor(&bpc, mega_k, 256, 0);
        hipDeviceGetAttribute(&ncu, hipDeviceAttributeMultiprocessorCount, 0);
        long cap = (long)((bpc < 1) ? 1 : bpc) * (long)ncu;
        nb_cache = (int)((cap < GRID_MAX) ? cap : GRID_MAX);
        if (nb_cache < 1) nb_cache = 1;
    }

    hipMemsetAsync(btot, 0, 512, stream);   // btot + barrier counters
    mega_k<<<nb_cache, 256, 0, stream>>>(x, ei, asrc, adst, atype,
                                         gW, gas, gad, gb, W1, b1, W2, b2, out,
                                         z16A, z16B, h3, zsA, zdA, zsB, zdB,
                                         offs, csr, bcnt, bpart, btot, bar, nb_cache);
}

// Round 4
// 231.199 us; speedup vs baseline: 3.4691x; 3.4691x over previous
//
#include <hip/hip_runtime.h>
#include <hip/hip_bf16.h>
#include <hip/hip_fp16.h>

#define N_NODES 10000
#define N_EDGES 640000
#define TOT_E   (N_EDGES + N_NODES)
#define HID     128
#define NEG_SLOPE 0.2f
#define N_ACT   4096

// ---- deterministic bucket counting-sort CSR build (no global atomics) ----
#define NBKT   250
#define NPB    40
#define P1_EPB 4096
#define P1_EPT 16
#define P1_BLOCKS 159
#define SLOTP  56
#define G_BLOCKS 313   // ceil(N_NODES/32) gemm-role blocks in merged kernel
#define FUSE_NPT 24    // fuse nodes/block
#define FUSE_B  417    // ceil(10000/24)

__global__ __launch_bounds__(256) void part1_k(const int* __restrict__ ei,
                                               unsigned* __restrict__ bpart,
                                               int* __restrict__ bcnt) {
    __shared__ int hist[256];
    __shared__ int lofs[256];
    __shared__ int sc[256];
    __shared__ unsigned stage[P1_EPB];
    __shared__ unsigned char bkt_of[P1_EPB];
    int t = threadIdx.x;
    hist[t] = 0;
    __syncthreads();

    unsigned pk[P1_EPT];
    int bk[P1_EPT];
    int e0 = blockIdx.x * P1_EPB;
#pragma unroll
    for (int i = 0; i < P1_EPT; i++) {
        int e = e0 + i * 256 + t;
        if (e < TOT_E) {
            int src, dst;
            if (e < N_EDGES) { src = ei[e]; dst = ei[N_EDGES + e]; }
            else             { src = e - N_EDGES; dst = src; }
            pk[i] = ((unsigned)dst << 16) | (unsigned)src;
            bk[i] = dst / NPB;
            atomicAdd(&hist[bk[i]], 1);
        } else bk[i] = -1;
    }
    __syncthreads();
    int v = hist[t];
    sc[t] = v;
    __syncthreads();
    for (int o = 1; o < 256; o <<= 1) {
        int u = (t >= o) ? sc[t - o] : 0;
        __syncthreads();
        sc[t] += u;
        __syncthreads();
    }
    lofs[t] = sc[t] - v;
    bcnt[blockIdx.x * 256 + t] = v;
    hist[t] = 0;
    __syncthreads();
#pragma unroll
    for (int i = 0; i < P1_EPT; i++) {
        if (bk[i] >= 0) {
            int p = atomicAdd(&hist[bk[i]], 1);
            int slot = lofs[bk[i]] + p;
            stage[slot] = pk[i];
            bkt_of[slot] = (unsigned char)bk[i];
        }
    }
    __syncthreads();
    int nv = min(P1_EPB, TOT_E - e0);
    for (int s = t; s < nv; s += 256) {
        int b = bkt_of[s];
        bpart[b * (P1_BLOCKS * SLOTP) + blockIdx.x * SLOTP + (s - lofs[b])] = stage[s];
    }
}

// -------- per-wave edge aggregate core: 2-deep pipelined row-load batches --------
__device__ __forceinline__ void agg_node(const __half2* __restrict__ z2,
                                         const float* __restrict__ zsi, float zdn,
                                         const int* __restrict__ csr, int o0, int deg,
                                         int lane, float& accx, float& accy, float& denom) {
    for (int base = 0; base < deg; base += 64) {
        int j = base + lane;
        int sreg = 0;
        float ex = 0.f;
        if (j < deg) {
            int s = csr[o0 + j];
            sreg = s;
            float e = zsi[s] + zdn;
            e = e > 0.f ? e : NEG_SLOPE * e;
            ex = __expf(e);
        }
        int cnt = min(64, deg - base);
        int nfull = cnt & ~7;
        int q = 0;
        if (nfull) {
            __half2 cur[8];
            float exc[8];
#pragma unroll
            for (int u = 0; u < 8; u++) {
                int sq = __builtin_amdgcn_readlane(sreg, u);
                exc[u] = __uint_as_float(__builtin_amdgcn_readlane(__float_as_uint(ex), u));
                cur[u] = z2[sq * 64];
            }
            for (q = 8; q < nfull; q += 8) {
                __half2 nxt[8];
                float exn[8];
#pragma unroll
                for (int u = 0; u < 8; u++) {
                    int sq = __builtin_amdgcn_readlane(sreg, q + u);
                    exn[u] = __uint_as_float(__builtin_amdgcn_readlane(__float_as_uint(ex), q + u));
                    nxt[u] = z2[sq * 64];   // next-batch loads fly over this batch's FMAs
                }
#pragma unroll
                for (int u = 0; u < 8; u++) {
                    denom += exc[u];
                    float2 vf = __half22float2(cur[u]);
                    accx = fmaf(exc[u], vf.x, accx);
                    accy = fmaf(exc[u], vf.y, accy);
                    cur[u] = nxt[u];
                    exc[u] = exn[u];
                }
            }
#pragma unroll
            for (int u = 0; u < 8; u++) {
                denom += exc[u];
                float2 vf = __half22float2(cur[u]);
                accx = fmaf(exc[u], vf.x, accx);
                accy = fmaf(exc[u], vf.y, accy);
            }
            q = nfull;
        }
        for (; q < cnt; q++) {
            int sq = __builtin_amdgcn_readlane(sreg, q);
            float exq = __uint_as_float(__builtin_amdgcn_readlane(__float_as_uint(ex), q));
            denom += exq;
            float2 vf = __half22float2(z2[sq * 64]);
            accx = fmaf(exq, vf.x, accx);
            accy = fmaf(exq, vf.y, accy);
        }
    }
}

__device__ __forceinline__ void gload_lds16(const float* g, float* l) {
    __builtin_amdgcn_global_load_lds(
        (const __attribute__((address_space(1))) void*)g,
        (__attribute__((address_space(3))) void*)l, 16, 0, 0);
}

// -------- merged: gemm0 (blocks < G_BLOCKS)  ||  part2 CSR finalize (rest) --------
__global__ __launch_bounds__(256) void g2_k(const float* __restrict__ A,
                                            const float* __restrict__ W,
                                            const float* __restrict__ avs,
                                            const float* __restrict__ avd,
                                            __half* __restrict__ z16,
                                            float* __restrict__ zs,
                                            float* __restrict__ zd,
                                            const unsigned* __restrict__ bpart,
                                            const int* __restrict__ bcnt,
                                            int* __restrict__ csr,
                                            int* __restrict__ offs) {
    __shared__ float smem[20480];   // 80 KB, carved per role
    int t = threadIdx.x;

    if (blockIdx.x < G_BLOCKS) {
        // ---------------- gemm role: one-shot LDS residency ----------------
        float* As = smem;            // 16 KB
        float* Ws = smem + 32 * HID; // 64 KB
        int w = t >> 6, lane = t & 63;
        int row0 = blockIdx.x * 32;
#pragma unroll
        for (int i = 0; i < 4; i++) {
            int chunk = w * 4 + i;
            long foff = (long)row0 * HID + chunk * 256;
            const float* g = ((foff + 256) <= (long)N_NODES * HID) ? (A + foff + lane * 4)
                                                                   : (A + lane * 4);
            gload_lds16(g, As + chunk * 256);
        }
#pragma unroll
        for (int i = 0; i < 16; i++) {
            int chunk = w * 16 + i;
            gload_lds16(W + chunk * 256 + lane * 4, Ws + chunk * 256);
        }
        __syncthreads();

        int tx = t & 31, ty = t >> 5;
        int r0 = ty * 4;
        float acc[4][4] = {{0.f}};
#pragma unroll 4
        for (int k4 = 0; k4 < 32; k4++) {
            float ak[4][4];
#pragma unroll
            for (int r = 0; r < 4; r++) {
                float4 a4 = *(const float4*)&As[(r0 + r) * HID + k4 * 4];
                ak[r][0] = a4.x; ak[r][1] = a4.y; ak[r][2] = a4.z; ak[r][3] = a4.w;
            }
            const float* Wb = &Ws[k4 * 4 * HID + tx * 4];
#pragma unroll
            for (int kk = 0; kk < 4; kk++) {
                float4 wv = *(const float4*)&Wb[kk * HID];
#pragma unroll
                for (int r = 0; r < 4; r++) {
                    acc[r][0] = fmaf(ak[r][kk], wv.x, acc[r][0]);
                    acc[r][1] = fmaf(ak[r][kk], wv.y, acc[r][1]);
                    acc[r][2] = fmaf(ak[r][kk], wv.z, acc[r][2]);
                    acc[r][3] = fmaf(ak[r][kk], wv.w, acc[r][3]);
                }
            }
        }
        float4 asv = *(const float4*)&avs[tx * 4];
        float4 adv = *(const float4*)&avd[tx * 4];
#pragma unroll
        for (int r = 0; r < 4; r++) {
            int row = row0 + r0 + r;
            if (row < N_NODES) {
                *(__half2*)&z16[row * HID + tx * 4]     = __floats2half2_rn(acc[r][0], acc[r][1]);
                *(__half2*)&z16[row * HID + tx * 4 + 2] = __floats2half2_rn(acc[r][2], acc[r][3]);
            }
            float ps = acc[r][0] * asv.x + acc[r][1] * asv.y + acc[r][2] * asv.z + acc[r][3] * asv.w;
            float pd = acc[r][0] * adv.x + acc[r][1] * adv.y + acc[r][2] * adv.z + acc[r][3] * adv.w;
#pragma unroll
            for (int o = 1; o < 32; o <<= 1) {
                ps += __shfl_xor(ps, o, 64);
                pd += __shfl_xor(pd, o, 64);
            }
            if (tx == 0 && row < N_NODES) { zs[row] = ps; zd[row] = pd; }
        }
    } else {
        // ---------------- part2 role: CSR finalize ----------------
        int b = blockIdx.x - G_BLOCKS;
        unsigned* ebuf = (unsigned*)smem;          // 16 KB
        int* sc    = (int*)(smem + 4096);          // 1 KB
        int* Ls    = sc + 256;                     // 1 KB
        int* nhist = Ls + 256;                     // 160 B
        __shared__ int bstart_s, cnt_s;

        int tot = 0;
        if (t < NBKT) {
            int t0 = 0, t1 = 0, t2 = 0, t3 = 0;
            int blk = 0;
            for (; blk + 4 <= P1_BLOCKS; blk += 4) {
                t0 += bcnt[(blk + 0) * 256 + t];
                t1 += bcnt[(blk + 1) * 256 + t];
                t2 += bcnt[(blk + 2) * 256 + t];
                t3 += bcnt[(blk + 3) * 256 + t];
            }
            for (; blk < P1_BLOCKS; blk++) t0 += bcnt[blk * 256 + t];
            tot = t0 + t1 + t2 + t3;
        }
        sc[t] = tot;
        __syncthreads();
        for (int o = 1; o < 256; o <<= 1) {
            int u = (t >= o) ? sc[t - o] : 0;
            __syncthreads();
            sc[t] += u;
            __syncthreads();
        }
        if (t == b) { bstart_s = sc[t] - tot; cnt_s = tot; }
        if (b == 0 && t == 255) offs[N_NODES] = sc[255];
        __syncthreads();

        int L = (t < P1_BLOCKS) ? bcnt[t * 256 + b] : 0;
        Ls[t] = L;
        sc[t] = L;
        __syncthreads();
        for (int o = 1; o < 256; o <<= 1) {
            int u = (t >= o) ? sc[t - o] : 0;
            __syncthreads();
            sc[t] += u;
            __syncthreads();
        }
        if (t < NPB) nhist[t] = 0;
        {
            int wv = t >> 6, lane = t & 63;
            const unsigned* bbase = bpart + b * (P1_BLOCKS * SLOTP);
            for (int r = wv; r < P1_BLOCKS; r += 4) {
                int Lr = Ls[r];
                if (lane < Lr) ebuf[(sc[r] - Lr) + lane] = bbase[r * SLOTP + lane];
            }
        }
        __syncthreads();

        int cnt = cnt_s;
        int n0 = b * NPB;
        for (int i = t; i < cnt; i += 256) atomicAdd(&nhist[(ebuf[i] >> 16) - n0], 1);
        __syncthreads();
        if (t < 64) {
            int v2 = (t < NPB) ? nhist[t] : 0;
            int s2 = v2;
            for (int o = 1; o < 64; o <<= 1) {
                int u = __shfl_up(s2, o, 64);
                if (t >= o) s2 += u;
            }
            if (t < NPB) {
                int ofs = bstart_s + s2 - v2;
                nhist[t] = ofs;
                offs[n0 + t] = ofs;
            }
        }
        __syncthreads();
        for (int i = t; i < cnt; i += 256) {
            unsigned pk = ebuf[i];
            int p = atomicAdd(&nhist[(pk >> 16) - n0], 1);
            csr[p] = pk & 0xFFFF;
        }
    }
}

// -------- fused: agg(l) -> hT in LDS -> gemm(l+1) --------
// One-shot 64 KB W via global_load_lds issued BEFORE agg; the entire agg
// phase covers the load latency. 24 nodes/block, 76 KB LDS, zero inner
// barriers in the gemm phase. 417 blocks @2/CU -> all resident.
__global__ __launch_bounds__(256) void fuse_k(const __half* __restrict__ z16i,
                                              const float* __restrict__ zsi,
                                              const float* __restrict__ zdi,
                                              const int* __restrict__ offs,
                                              const int* __restrict__ csr,
                                              const float* __restrict__ bprev,
                                              const float* __restrict__ W,
                                              const float* __restrict__ avs,
                                              const float* __restrict__ avd,
                                              __half* __restrict__ z16o,
                                              float* __restrict__ zso,
                                              float* __restrict__ zdo) {
    __shared__ float hT[FUSE_NPT][HID];  // 12 KB
    __shared__ float Ws[HID * HID];      // 64 KB
    int t = threadIdx.x;
    int w = t >> 6, lane = t & 63;
    int n0 = blockIdx.x * FUSE_NPT;

    // W: 64 chunks of 256 floats; wave w issues 16 — loads fly during agg
#pragma unroll
    for (int i = 0; i < 16; i++) {
        int chunk = w * 16 + i;
        gload_lds16(W + chunk * 256 + lane * 4, Ws + chunk * 256);
    }

    const __half2* z2 = (const __half2*)z16i + lane;
    float2 bv = *(const float2*)&bprev[2 * lane];
#pragma unroll
    for (int i = 0; i < 6; i++) {
        int ln = w * 6 + i;
        int n = n0 + ln;
        if (n < N_NODES) {
            int o0 = offs[n];
            int deg = offs[n + 1] - o0;
            float zdn = zdi[n];
            float accx = 0.f, accy = 0.f, denom = 0.f;
            agg_node(z2, zsi, zdn, csr, o0, deg, lane, accx, accy, denom);
            float inv = 1.0f / denom;
            float vx = accx * inv + bv.x;
            float vy = accy * inv + bv.y;
            float2 hv;
            hv.x = vx > 0.f ? vx : 0.f;
            hv.y = vy > 0.f ? vy : 0.f;
            *(float2*)&hT[ln][2 * lane] = hv;
        }
    }
    __syncthreads();   // hT published; W loads long since landed (vmcnt drained)

    // gemm: 24 x 128 x 128, pure LDS, no barriers
    int tx = t & 31, ty = t >> 5;
    float acc[3][4] = {{0.f}};
#pragma unroll 4
    for (int k4 = 0; k4 < 32; k4++) {
        float4 av[3];
#pragma unroll
        for (int u = 0; u < 3; u++)
            av[u] = *(const float4*)&hT[ty * 3 + u][k4 * 4];
        const float* Wb = &Ws[k4 * 4 * HID + tx * 4];
#pragma unroll
        for (int kk = 0; kk < 4; kk++) {
            float4 wv = *(const float4*)&Wb[kk * HID];
#pragma unroll
            for (int u = 0; u < 3; u++) {
                float f = (kk == 0) ? av[u].x : (kk == 1) ? av[u].y
                         : (kk == 2) ? av[u].z : av[u].w;
                acc[u][0] = fmaf(f, wv.x, acc[u][0]);
                acc[u][1] = fmaf(f, wv.y, acc[u][1]);
                acc[u][2] = fmaf(f, wv.z, acc[u][2]);
                acc[u][3] = fmaf(f, wv.w, acc[u][3]);
            }
        }
    }
    float4 asv = *(const float4*)&avs[tx * 4];
    float4 adv = *(const float4*)&avd[tx * 4];
#pragma unroll
    for (int u = 0; u < 3; u++) {
        int row = n0 + ty * 3 + u;
        float ps = acc[u][0] * asv.x + acc[u][1] * asv.y + acc[u][2] * asv.z + acc[u][3] * asv.w;
        float pd = acc[u][0] * adv.x + acc[u][1] * adv.y + acc[u][2] * adv.z + acc[u][3] * adv.w;
#pragma unroll
        for (int o = 1; o < 32; o <<= 1) {
            ps += __shfl_xor(ps, o, 64);
            pd += __shfl_xor(pd, o, 64);
        }
        if (row < N_NODES) {
            *(__half2*)&z16o[row * HID + tx * 4]     = __floats2half2_rn(acc[u][0], acc[u][1]);
            *(__half2*)&z16o[row * HID + tx * 4 + 2] = __floats2half2_rn(acc[u][2], acc[u][3]);
            if (tx == 0) { zso[row] = ps; zdo[row] = pd; }
        }
    }
}

// -------- final-layer aggregate -> h3 --------

__global__ __launch_bounds__(256) void agg_k(const __half* __restrict__ z16,
                                             const float* __restrict__ zs,
                                             const float* __restrict__ zd,
                                             const int* __restrict__ offs,
                                             const int* __restrict__ csr,
                                             const float* __restrict__ b,
                                             float* __restrict__ hout) {
    int t = threadIdx.x;
    int w = t >> 6, lane = t & 63;
    int n = blockIdx.x * 4 + w;
    if (n >= N_NODES) return;
    int o0 = offs[n];
    int deg = offs[n + 1] - o0;
    float zdn = zd[n];
    const __half2* z2 = (const __half2*)z16 + lane;
    float accx = 0.f, accy = 0.f, denom = 0.f;
    agg_node(z2, zs, zdn, csr, o0, deg, lane, accx, accy, denom);
    float inv = 1.0f / denom;
    float2 bv = *(const float2*)&b[2 * lane];
    float vx = accx * inv + bv.x;
    float vy = accy * inv + bv.y;
    float2 o;
    o.x = vx > 0.f ? vx : 0.f;
    o.y = vy > 0.f ? vy : 0.f;
    *(float2*)&hout[n * HID + 2 * lane] = o;
}

// -------- action scoring: tiled GEMM, 16 actions/block × 256 blocks, dbuf W1 --------

#define SC_APB 16

__global__ __launch_bounds__(256) void score_k(const float* __restrict__ h,
                                               const int* __restrict__ asrc,
                                               const int* __restrict__ adst,
                                               const int* __restrict__ atype,
                                               const float* __restrict__ W1,
                                               const float* __restrict__ b1,
                                               const float* __restrict__ W2,
                                               const float* __restrict__ b2,
                                               float* __restrict__ out) {
    __shared__ float featT[257][SC_APB + 1];   // [k][action], padded: 17.5 KB
    __shared__ float Wc[2][32 * HID];          // 32 KB
    int t = threadIdx.x;
    int a0 = blockIdx.x * SC_APB;

    float4 wreg[4];
    {
        const float4* Wg = (const float4*)W1;
#pragma unroll
        for (int i = 0; i < 4; i++) wreg[i] = Wg[t + 256 * i];
    }
    for (int idx = t; idx < SC_APB * 128; idx += 256) {
        int a = idx >> 7, c = idx & 127;
        featT[c][a]       = h[asrc[a0 + a] * HID + c];
        featT[128 + c][a] = h[adst[a0 + a] * HID + c];
    }
    if (t < SC_APB) featT[256][t] = (float)atype[a0 + t];

    int cg = t & 31, ap = t >> 5;
    float4 bv = *(const float4*)&b1[cg * 4];
    float acc0[4] = {bv.x, bv.y, bv.z, bv.w};
    float acc1[4] = {bv.x, bv.y, bv.z, bv.w};

    for (int c = 0; c < 8; c++) {
        float4* dstb = (float4*)Wc[c & 1];
#pragma unroll
        for (int i = 0; i < 4; i++) dstb[t + 256 * i] = wreg[i];
        __syncthreads();
        if (c + 1 < 8) {
            const float4* Wg = (const float4*)(W1 + (c + 1) * 32 * HID);
#pragma unroll
            for (int i = 0; i < 4; i++) wreg[i] = Wg[t + 256 * i];
        }
        const float* Wb = Wc[c & 1];
        const float* fT = &featT[c * 32][0];
#pragma unroll 8
        for (int kk = 0; kk < 32; kk++) {
            float4 wv = *(const float4*)&Wb[kk * HID + cg * 4];
            float f0 = fT[kk * (SC_APB + 1) + ap * 2];
            float f1 = fT[kk * (SC_APB + 1) + ap * 2 + 1];
            acc0[0] = fmaf(f0, wv.x, acc0[0]);
            acc0[1] = fmaf(f0, wv.y, acc0[1]);
            acc0[2] = fmaf(f0, wv.z, acc0[2]);
            acc0[3] = fmaf(f0, wv.w, acc0[3]);
            acc1[0] = fmaf(f1, wv.x, acc1[0]);
            acc1[1] = fmaf(f1, wv.y, acc1[1]);
            acc1[2] = fmaf(f1, wv.z, acc1[2]);
            acc1[3] = fmaf(f1, wv.w, acc1[3]);
        }
    }
    {
        float4 wv = *(const float4*)&W1[256 * HID + cg * 4];
        float f0 = featT[256][ap * 2];
        float f1 = featT[256][ap * 2 + 1];
        acc0[0] = fmaf(f0, wv.x, acc0[0]); acc0[1] = fmaf(f0, wv.y, acc0[1]);
        acc0[2] = fmaf(f0, wv.z, acc0[2]); acc0[3] = fmaf(f0, wv.w, acc0[3]);
        acc1[0] = fmaf(f1, wv.x, acc1[0]); acc1[1] = fmaf(f1, wv.y, acc1[1]);
        acc1[2] = fmaf(f1, wv.z, acc1[2]); acc1[3] = fmaf(f1, wv.w, acc1[3]);
    }
    float4 w2v = *(const float4*)&W2[cg * 4];
    float v0 = 0.f, v1 = 0.f;
    v0 += (acc0[0] > 0.f ? acc0[0] : 0.f) * w2v.x;
    v0 += (acc0[1] > 0.f ? acc0[1] : 0.f) * w2v.y;
    v0 += (acc0[2] > 0.f ? acc0[2] : 0.f) * w2v.z;
    v0 += (acc0[3] > 0.f ? acc0[3] : 0.f) * w2v.w;
    v1 += (acc1[0] > 0.f ? acc1[0] : 0.f) * w2v.x;
    v1 += (acc1[1] > 0.f ? acc1[1] : 0.f) * w2v.y;
    v1 += (acc1[2] > 0.f ? acc1[2] : 0.f) * w2v.z;
    v1 += (acc1[3] > 0.f ? acc1[3] : 0.f) * w2v.w;
#pragma unroll
    for (int o = 1; o < 32; o <<= 1) {
        v0 += __shfl_xor(v0, o, 64);
        v1 += __shfl_xor(v1, o, 64);
    }
    if (cg == 0) {
        out[a0 + ap * 2]     = v0 + b2[0];
        out[a0 + ap * 2 + 1] = v1 + b2[0];
    }
}

// ---------------- launch ----------------

extern "C" void kernel_launch(void* const* d_in, const int* in_sizes, int n_in,
                              void* d_out, int out_size, void* d_ws, size_t ws_size,
                              hipStream_t stream) {
    const float* x   = (const float*)d_in[0];
    const int* ei    = (const int*)d_in[1];
    const int* asrc  = (const int*)d_in[2];
    const int* adst  = (const int*)d_in[3];
    const int* atype = (const int*)d_in[4];
    const float* gW  = (const float*)d_in[5];
    const float* gas = (const float*)d_in[6];
    const float* gad = (const float*)d_in[7];
    const float* gb  = (const float*)d_in[8];
    const float* W1  = (const float*)d_in[9];
    const float* b1  = (const float*)d_in[10];
    const float* W2  = (const float*)d_in[11];
    const float* b2  = (const float*)d_in[12];
    float* out = (float*)d_out;

    __half* z16A = (__half*)d_ws;                       // 2.56 MB
    __half* z16B = z16A + N_NODES * HID;                // 2.56 MB
    float* h3   = (float*)(z16B + N_NODES * HID);       // 5.12 MB
    float* zsA  = h3 + N_NODES * HID;
    float* zdA  = zsA + N_NODES;
    float* zsB  = zdA + N_NODES;
    float* zdB  = zsB + N_NODES;
    int* offs   = (int*)(zdB + N_NODES);
    int* csr    = offs + (N_NODES + 1);
    int* bcnt   = csr + TOT_E;
    unsigned* bpart = (unsigned*)(bcnt + P1_BLOCKS * 256);

    part1_k<<<P1_BLOCKS, 256, 0, stream>>>(ei, bpart, bcnt);
    g2_k<<<G_BLOCKS + NBKT, 256, 0, stream>>>(x, gW, gas, gad, z16A, zsA, zdA,
                                              bpart, bcnt, csr, offs);

    fuse_k<<<FUSE_B, 256, 0, stream>>>(z16A, zsA, zdA, offs, csr, gb,
                                       gW + 1 * HID * HID, gas + 1 * HID, gad + 1 * HID,
                                       z16B, zsB, zdB);
    fuse_k<<<FUSE_B, 256, 0, stream>>>(z16B, zsB, zdB, offs, csr, gb + 1 * HID,
                                       gW + 2 * HID * HID, gas + 2 * HID, gad + 2 * HID,
                                       z16A, zsA, zdA);
    agg_k<<<(N_NODES + 3) / 4, 256, 0, stream>>>(z16A, zsA, zdA, offs, csr,
                                                 gb + 2 * HID, h3);
    score_k<<<N_ACT / SC_APB, 256, 0, stream>>>(h3, asrc, adst, atype,
                                                W1, b1, W2, b2, out);
}

// Round 5
// 221.943 us; speedup vs baseline: 3.6138x; 1.0417x over previous
//
#include <hip/hip_runtime.h>
#include <hip/hip_bf16.h>
#include <hip/hip_fp16.h>

#define N_NODES 10000
#define N_EDGES 640000
#define TOT_E   (N_EDGES + N_NODES)
#define HID     128
#define NEG_SLOPE 0.2f
#define N_ACT   4096

// ---- deterministic bucket counting-sort CSR build (no global atomics) ----
#define NBKT   250
#define NPB    40
#define P1_EPB 4096
#define P1_EPT 16
#define P1_BLOCKS 159
#define SLOTP  56
#define G_BLOCKS 313   // ceil(N_NODES/32) gemm-role blocks in merged kernel

__global__ __launch_bounds__(256) void part1_k(const int* __restrict__ ei,
                                               unsigned* __restrict__ bpart,
                                               int* __restrict__ bcnt) {
    __shared__ int hist[256];
    __shared__ int lofs[256];
    __shared__ int sc[256];
    __shared__ unsigned stage[P1_EPB];
    __shared__ unsigned char bkt_of[P1_EPB];
    int t = threadIdx.x;
    hist[t] = 0;
    __syncthreads();

    unsigned pk[P1_EPT];
    int bk[P1_EPT];
    int e0 = blockIdx.x * P1_EPB;
#pragma unroll
    for (int i = 0; i < P1_EPT; i++) {
        int e = e0 + i * 256 + t;
        if (e < TOT_E) {
            int src, dst;
            if (e < N_EDGES) { src = ei[e]; dst = ei[N_EDGES + e]; }
            else             { src = e - N_EDGES; dst = src; }
            pk[i] = ((unsigned)dst << 16) | (unsigned)src;
            bk[i] = dst / NPB;
            atomicAdd(&hist[bk[i]], 1);
        } else bk[i] = -1;
    }
    __syncthreads();
    int v = hist[t];
    sc[t] = v;
    __syncthreads();
    for (int o = 1; o < 256; o <<= 1) {
        int u = (t >= o) ? sc[t - o] : 0;
        __syncthreads();
        sc[t] += u;
        __syncthreads();
    }
    lofs[t] = sc[t] - v;
    bcnt[blockIdx.x * 256 + t] = v;
    hist[t] = 0;
    __syncthreads();
#pragma unroll
    for (int i = 0; i < P1_EPT; i++) {
        if (bk[i] >= 0) {
            int p = atomicAdd(&hist[bk[i]], 1);
            int slot = lofs[bk[i]] + p;
            stage[slot] = pk[i];
            bkt_of[slot] = (unsigned char)bk[i];
        }
    }
    __syncthreads();
    int nv = min(P1_EPB, TOT_E - e0);
    for (int s = t; s < nv; s += 256) {
        int b = bkt_of[s];
        bpart[b * (P1_BLOCKS * SLOTP) + blockIdx.x * SLOTP + (s - lofs[b])] = stage[s];
    }
}

// -------- per-wave edge aggregate core --------
// denom via 6-step butterfly (lane-uniform), 2-deep pipelined row loads.
__device__ __forceinline__ void agg_node(const __half2* __restrict__ z2,
                                         const float* __restrict__ zsi, float zdn,
                                         const int* __restrict__ csr, int o0, int deg,
                                         int lane, float& accx, float& accy, float& denom) {
    for (int base = 0; base < deg; base += 64) {
        int j = base + lane;
        int sreg = 0;
        float ex = 0.f;
        if (j < deg) {
            int s = csr[o0 + j];
            sreg = s;
            float e = zsi[s] + zdn;
            e = e > 0.f ? e : NEG_SLOPE * e;
            ex = __expf(e);
        }
        // batch denom: butterfly reduce (ex=0 for inactive lanes)
        {
            float bs = ex;
#pragma unroll
            for (int o = 1; o < 64; o <<= 1) bs += __shfl_xor(bs, o, 64);
            denom += bs;
        }
        int cnt = min(64, deg - base);
        int nfull = cnt & ~7;
        int q = 0;
        if (nfull) {
            __half2 cur[8];
            float exc[8];
#pragma unroll
            for (int u = 0; u < 8; u++) {
                int sq = __builtin_amdgcn_readlane(sreg, u);
                exc[u] = __uint_as_float(__builtin_amdgcn_readlane(__float_as_uint(ex), u));
                cur[u] = z2[sq * 64];
            }
            for (q = 8; q < nfull; q += 8) {
                __half2 nxt[8];
                float exn[8];
#pragma unroll
                for (int u = 0; u < 8; u++) {
                    int sq = __builtin_amdgcn_readlane(sreg, q + u);
                    exn[u] = __uint_as_float(__builtin_amdgcn_readlane(__float_as_uint(ex), q + u));
                    nxt[u] = z2[sq * 64];   // next-batch loads fly over this batch's FMAs
                }
#pragma unroll
                for (int u = 0; u < 8; u++) {
                    float2 vf = __half22float2(cur[u]);
                    accx = fmaf(exc[u], vf.x, accx);
                    accy = fmaf(exc[u], vf.y, accy);
                    cur[u] = nxt[u];
                    exc[u] = exn[u];
                }
            }
#pragma unroll
            for (int u = 0; u < 8; u++) {
                float2 vf = __half22float2(cur[u]);
                accx = fmaf(exc[u], vf.x, accx);
                accy = fmaf(exc[u], vf.y, accy);
            }
            q = nfull;
        }
        for (; q < cnt; q++) {
            int sq = __builtin_amdgcn_readlane(sreg, q);
            float exq = __uint_as_float(__builtin_amdgcn_readlane(__float_as_uint(ex), q));
            float2 vf = __half22float2(z2[sq * 64]);
            accx = fmaf(exq, vf.x, accx);
            accy = fmaf(exq, vf.y, accy);
        }
    }
}

__device__ __forceinline__ void gload_lds16(const float* g, float* l) {
    __builtin_amdgcn_global_load_lds(
        (const __attribute__((address_space(1))) void*)g,
        (__attribute__((address_space(3))) void*)l, 16, 0, 0);
}

// -------- merged: gemm0 (blocks < G_BLOCKS)  ||  part2 CSR finalize (rest) --------
__global__ __launch_bounds__(256) void g2_k(const float* __restrict__ A,
                                            const float* __restrict__ W,
                                            const float* __restrict__ avs,
                                            const float* __restrict__ avd,
                                            __half* __restrict__ z16,
                                            float* __restrict__ zs,
                                            float* __restrict__ zd,
                                            const unsigned* __restrict__ bpart,
                                            const int* __restrict__ bcnt,
                                            int* __restrict__ csr,
                                            int* __restrict__ offs) {
    __shared__ float smem[20480];   // 80 KB, carved per role
    int t = threadIdx.x;

    if (blockIdx.x < G_BLOCKS) {
        // ---------------- gemm role: one-shot LDS residency ----------------
        float* As = smem;            // 16 KB
        float* Ws = smem + 32 * HID; // 64 KB
        int w = t >> 6, lane = t & 63;
        int row0 = blockIdx.x * 32;
#pragma unroll
        for (int i = 0; i < 4; i++) {
            int chunk = w * 4 + i;
            long foff = (long)row0 * HID + chunk * 256;
            const float* g = ((foff + 256) <= (long)N_NODES * HID) ? (A + foff + lane * 4)
                                                                   : (A + lane * 4);
            gload_lds16(g, As + chunk * 256);
        }
#pragma unroll
        for (int i = 0; i < 16; i++) {
            int chunk = w * 16 + i;
            gload_lds16(W + chunk * 256 + lane * 4, Ws + chunk * 256);
        }
        __syncthreads();

        int tx = t & 31, ty = t >> 5;
        int r0 = ty * 4;
        float acc[4][4] = {{0.f}};
#pragma unroll 4
        for (int k4 = 0; k4 < 32; k4++) {
            float ak[4][4];
#pragma unroll
            for (int r = 0; r < 4; r++) {
                float4 a4 = *(const float4*)&As[(r0 + r) * HID + k4 * 4];
                ak[r][0] = a4.x; ak[r][1] = a4.y; ak[r][2] = a4.z; ak[r][3] = a4.w;
            }
            const float* Wb = &Ws[k4 * 4 * HID + tx * 4];
#pragma unroll
            for (int kk = 0; kk < 4; kk++) {
                float4 wv = *(const float4*)&Wb[kk * HID];
#pragma unroll
                for (int r = 0; r < 4; r++) {
                    acc[r][0] = fmaf(ak[r][kk], wv.x, acc[r][0]);
                    acc[r][1] = fmaf(ak[r][kk], wv.y, acc[r][1]);
                    acc[r][2] = fmaf(ak[r][kk], wv.z, acc[r][2]);
                    acc[r][3] = fmaf(ak[r][kk], wv.w, acc[r][3]);
                }
            }
        }
        float4 asv = *(const float4*)&avs[tx * 4];
        float4 adv = *(const float4*)&avd[tx * 4];
#pragma unroll
        for (int r = 0; r < 4; r++) {
            int row = row0 + r0 + r;
            if (row < N_NODES) {
                *(__half2*)&z16[row * HID + tx * 4]     = __floats2half2_rn(acc[r][0], acc[r][1]);
                *(__half2*)&z16[row * HID + tx * 4 + 2] = __floats2half2_rn(acc[r][2], acc[r][3]);
            }
            float ps = acc[r][0] * asv.x + acc[r][1] * asv.y + acc[r][2] * asv.z + acc[r][3] * asv.w;
            float pd = acc[r][0] * adv.x + acc[r][1] * adv.y + acc[r][2] * adv.z + acc[r][3] * adv.w;
#pragma unroll
            for (int o = 1; o < 32; o <<= 1) {
                ps += __shfl_xor(ps, o, 64);
                pd += __shfl_xor(pd, o, 64);
            }
            if (tx == 0 && row < N_NODES) { zs[row] = ps; zd[row] = pd; }
        }
    } else {
        // ---------------- part2 role: CSR finalize ----------------
        int b = blockIdx.x - G_BLOCKS;
        unsigned* ebuf = (unsigned*)smem;          // 16 KB
        int* sc    = (int*)(smem + 4096);          // 1 KB
        int* Ls    = sc + 256;                     // 1 KB
        int* nhist = Ls + 256;                     // 160 B
        __shared__ int bstart_s, cnt_s;

        int tot = 0;
        if (t < NBKT) {
            int t0 = 0, t1 = 0, t2 = 0, t3 = 0;
            int blk = 0;
            for (; blk + 4 <= P1_BLOCKS; blk += 4) {
                t0 += bcnt[(blk + 0) * 256 + t];
                t1 += bcnt[(blk + 1) * 256 + t];
                t2 += bcnt[(blk + 2) * 256 + t];
                t3 += bcnt[(blk + 3) * 256 + t];
            }
            for (; blk < P1_BLOCKS; blk++) t0 += bcnt[blk * 256 + t];
            tot = t0 + t1 + t2 + t3;
        }
        sc[t] = tot;
        __syncthreads();
        for (int o = 1; o < 256; o <<= 1) {
            int u = (t >= o) ? sc[t - o] : 0;
            __syncthreads();
            sc[t] += u;
            __syncthreads();
        }
        if (t == b) { bstart_s = sc[t] - tot; cnt_s = tot; }
        if (b == 0 && t == 255) offs[N_NODES] = sc[255];
        __syncthreads();

        int L = (t < P1_BLOCKS) ? bcnt[t * 256 + b] : 0;
        Ls[t] = L;
        sc[t] = L;
        __syncthreads();
        for (int o = 1; o < 256; o <<= 1) {
            int u = (t >= o) ? sc[t - o] : 0;
            __syncthreads();
            sc[t] += u;
            __syncthreads();
        }
        if (t < NPB) nhist[t] = 0;
        {
            int wv = t >> 6, lane = t & 63;
            const unsigned* bbase = bpart + b * (P1_BLOCKS * SLOTP);
            for (int r = wv; r < P1_BLOCKS; r += 4) {
                int Lr = Ls[r];
                if (lane < Lr) ebuf[(sc[r] - Lr) + lane] = bbase[r * SLOTP + lane];
            }
        }
        __syncthreads();

        int cnt = cnt_s;
        int n0 = b * NPB;
        for (int i = t; i < cnt; i += 256) atomicAdd(&nhist[(ebuf[i] >> 16) - n0], 1);
        __syncthreads();
        if (t < 64) {
            int v2 = (t < NPB) ? nhist[t] : 0;
            int s2 = v2;
            for (int o = 1; o < 64; o <<= 1) {
                int u = __shfl_up(s2, o, 64);
                if (t >= o) s2 += u;
            }
            if (t < NPB) {
                int ofs = bstart_s + s2 - v2;
                nhist[t] = ofs;
                offs[n0 + t] = ofs;
            }
        }
        __syncthreads();
        for (int i = t; i < cnt; i += 256) {
            unsigned pk = ebuf[i];
            int p = atomicAdd(&nhist[(pk >> 16) - n0], 1);
            csr[p] = pk & 0xFFFF;
        }
    }
}

// -------- fused: agg(l) -> hT in LDS -> gemm(l+1); 16 nodes/block, dbuf W --------
// 40 KB LDS -> 4 blocks/CU: occupancy for the latency-bound agg phase.
// W chunk0 register-prefetch flies across the agg phase.
__global__ __launch_bounds__(256) void fuse_k(const __half* __restrict__ z16i,
                                              const float* __restrict__ zsi,
                                              const float* __restrict__ zdi,
                                              const int* __restrict__ offs,
                                              const int* __restrict__ csr,
                                              const float* __restrict__ bprev,
                                              const float* __restrict__ W,
                                              const float* __restrict__ avs,
                                              const float* __restrict__ avd,
                                              __half* __restrict__ z16o,
                                              float* __restrict__ zso,
                                              float* __restrict__ zdo) {
    __shared__ float hT[16][HID];        // 8 KB
    __shared__ float Wc[2][32 * HID];    // 32 KB
    int t = threadIdx.x;
    int w = t >> 6, lane = t & 63;
    int n0 = blockIdx.x * 16;
    float4 wreg[4];
    {
        const float4* Wg = (const float4*)W;
#pragma unroll
        for (int i = 0; i < 4; i++) wreg[i] = Wg[t + 256 * i];
    }
    const __half2* z2 = (const __half2*)z16i + lane;

    float2 bv = *(const float2*)&bprev[2 * lane];
#pragma unroll
    for (int i = 0; i < 4; i++) {
        int ln = w * 4 + i;
        int n = n0 + ln;
        int o0 = offs[n];
        int deg = offs[n + 1] - o0;
        float zdn = zdi[n];
        float accx = 0.f, accy = 0.f, denom = 0.f;
        agg_node(z2, zsi, zdn, csr, o0, deg, lane, accx, accy, denom);
        float inv = 1.0f / denom;
        float vx = accx * inv + bv.x;
        float vy = accy * inv + bv.y;
        float2 hv;
        hv.x = vx > 0.f ? vx : 0.f;
        hv.y = vy > 0.f ? vy : 0.f;
        *(float2*)&hT[ln][2 * lane] = hv;
    }

    int tx = t & 31, ty = t >> 5;
    int r0 = ty * 2, r1 = ty * 2 + 1;
    float acc[2][4] = {{0.f}};
    for (int c = 0; c < 4; c++) {
        float4* dstb = (float4*)Wc[c & 1];
#pragma unroll
        for (int i = 0; i < 4; i++) dstb[t + 256 * i] = wreg[i];
        __syncthreads();                 // publishes Wc chunk c (and hT on c==0)
        if (c + 1 < 4) {
            const float4* Wg = (const float4*)(W + (c + 1) * 32 * HID);
#pragma unroll
            for (int i = 0; i < 4; i++) wreg[i] = Wg[t + 256 * i];
        }
        const float* Wb = Wc[c & 1];
        const float* h0 = &hT[r0][c * 32];
        const float* h1 = &hT[r1][c * 32];
#pragma unroll 8
        for (int kk = 0; kk < 32; kk++) {
            float f0 = h0[kk], f1 = h1[kk];
            float4 wv = *(const float4*)&Wb[kk * HID + tx * 4];
            acc[0][0] = fmaf(f0, wv.x, acc[0][0]);
            acc[0][1] = fmaf(f0, wv.y, acc[0][1]);
            acc[0][2] = fmaf(f0, wv.z, acc[0][2]);
            acc[0][3] = fmaf(f0, wv.w, acc[0][3]);
            acc[1][0] = fmaf(f1, wv.x, acc[1][0]);
            acc[1][1] = fmaf(f1, wv.y, acc[1][1]);
            acc[1][2] = fmaf(f1, wv.z, acc[1][2]);
            acc[1][3] = fmaf(f1, wv.w, acc[1][3]);
        }
    }
    float4 asv = *(const float4*)&avs[tx * 4];
    float4 adv = *(const float4*)&avd[tx * 4];
#pragma unroll
    for (int r = 0; r < 2; r++) {
        int row = n0 + (r ? r1 : r0);
        *(__half2*)&z16o[row * HID + tx * 4]     = __floats2half2_rn(acc[r][0], acc[r][1]);
        *(__half2*)&z16o[row * HID + tx * 4 + 2] = __floats2half2_rn(acc[r][2], acc[r][3]);
        float ps = acc[r][0] * asv.x + acc[r][1] * asv.y + acc[r][2] * asv.z + acc[r][3] * asv.w;
        float pd = acc[r][0] * adv.x + acc[r][1] * adv.y + acc[r][2] * adv.z + acc[r][3] * adv.w;
#pragma unroll
        for (int o = 1; o < 32; o <<= 1) {
            ps += __shfl_xor(ps, o, 64);
            pd += __shfl_xor(pd, o, 64);
        }
        if (tx == 0) { zso[row] = ps; zdo[row] = pd; }
    }
}

// -------- final-layer aggregate -> h3 --------

__global__ __launch_bounds__(256) void agg_k(const __half* __restrict__ z16,
                                             const float* __restrict__ zs,
                                             const float* __restrict__ zd,
                                             const int* __restrict__ offs,
                                             const int* __restrict__ csr,
                                             const float* __restrict__ b,
                                             float* __restrict__ hout) {
    int t = threadIdx.x;
    int w = t >> 6, lane = t & 63;
    int n = blockIdx.x * 4 + w;
    if (n >= N_NODES) return;
    int o0 = offs[n];
    int deg = offs[n + 1] - o0;
    float zdn = zd[n];
    const __half2* z2 = (const __half2*)z16 + lane;
    float accx = 0.f, accy = 0.f, denom = 0.f;
    agg_node(z2, zs, zdn, csr, o0, deg, lane, accx, accy, denom);
    float inv = 1.0f / denom;
    float2 bv = *(const float2*)&b[2 * lane];
    float vx = accx * inv + bv.x;
    float vy = accy * inv + bv.y;
    float2 o;
    o.x = vx > 0.f ? vx : 0.f;
    o.y = vy > 0.f ? vy : 0.f;
    *(float2*)&hout[n * HID + 2 * lane] = o;
}

// -------- action scoring: tiled GEMM, 16 actions/block × 256 blocks, dbuf W1 --------

#define SC_APB 16

__global__ __launch_bounds__(256) void score_k(const float* __restrict__ h,
                                               const int* __restrict__ asrc,
                                               const int* __restrict__ adst,
                                               const int* __restrict__ atype,
                                               const float* __restrict__ W1,
                                               const float* __restrict__ b1,
                                               const float* __restrict__ W2,
                                               const float* __restrict__ b2,
                                               float* __restrict__ out) {
    __shared__ float featT[257][SC_APB + 1];   // [k][action], padded: 17.5 KB
    __shared__ float Wc[2][32 * HID];          // 32 KB
    int t = threadIdx.x;
    int a0 = blockIdx.x * SC_APB;

    float4 wreg[4];
    {
        const float4* Wg = (const float4*)W1;
#pragma unroll
        for (int i = 0; i < 4; i++) wreg[i] = Wg[t + 256 * i];
    }
    for (int idx = t; idx < SC_APB * 128; idx += 256) {
        int a = idx >> 7, c = idx & 127;
        featT[c][a]       = h[asrc[a0 + a] * HID + c];
        featT[128 + c][a] = h[adst[a0 + a] * HID + c];
    }
    if (t < SC_APB) featT[256][t] = (float)atype[a0 + t];

    int cg = t & 31, ap = t >> 5;
    float4 bv = *(const float4*)&b1[cg * 4];
    float acc0[4] = {bv.x, bv.y, bv.z, bv.w};
    float acc1[4] = {bv.x, bv.y, bv.z, bv.w};

    for (int c = 0; c < 8; c++) {
        float4* dstb = (float4*)Wc[c & 1];
#pragma unroll
        for (int i = 0; i < 4; i++) dstb[t + 256 * i] = wreg[i];
        __syncthreads();
        if (c + 1 < 8) {
            const float4* Wg = (const float4*)(W1 + (c + 1) * 32 * HID);
#pragma unroll
            for (int i = 0; i < 4; i++) wreg[i] = Wg[t + 256 * i];
        }
        const float* Wb = Wc[c & 1];
        const float* fT = &featT[c * 32][0];
#pragma unroll 8
        for (int kk = 0; kk < 32; kk++) {
            float4 wv = *(const float4*)&Wb[kk * HID + cg * 4];
            float f0 = fT[kk * (SC_APB + 1) + ap * 2];
            float f1 = fT[kk * (SC_APB + 1) + ap * 2 + 1];
            acc0[0] = fmaf(f0, wv.x, acc0[0]);
            acc0[1] = fmaf(f0, wv.y, acc0[1]);
            acc0[2] = fmaf(f0, wv.z, acc0[2]);
            acc0[3] = fmaf(f0, wv.w, acc0[3]);
            acc1[0] = fmaf(f1, wv.x, acc1[0]);
            acc1[1] = fmaf(f1, wv.y, acc1[1]);
            acc1[2] = fmaf(f1, wv.z, acc1[2]);
            acc1[3] = fmaf(f1, wv.w, acc1[3]);
        }
    }
    {
        float4 wv = *(const float4*)&W1[256 * HID + cg * 4];
        float f0 = featT[256][ap * 2];
        float f1 = featT[256][ap * 2 + 1];
        acc0[0] = fmaf(f0, wv.x, acc0[0]); acc0[1] = fmaf(f0, wv.y, acc0[1]);
        acc0[2] = fmaf(f0, wv.z, acc0[2]); acc0[3] = fmaf(f0, wv.w, acc0[3]);
        acc1[0] = fmaf(f1, wv.x, acc1[0]); acc1[1] = fmaf(f1, wv.y, acc1[1]);
        acc1[2] = fmaf(f1, wv.z, acc1[2]); acc1[3] = fmaf(f1, wv.w, acc1[3]);
    }
    float4 w2v = *(const float4*)&W2[cg * 4];
    float v0 = 0.f, v1 = 0.f;
    v0 += (acc0[0] > 0.f ? acc0[0] : 0.f) * w2v.x;
    v0 += (acc0[1] > 0.f ? acc0[1] : 0.f) * w2v.y;
    v0 += (acc0[2] > 0.f ? acc0[2] : 0.f) * w2v.z;
    v0 += (acc0[3] > 0.f ? acc0[3] : 0.f) * w2v.w;
    v1 += (acc1[0] > 0.f ? acc1[0] : 0.f) * w2v.x;
    v1 += (acc1[1] > 0.f ? acc1[1] : 0.f) * w2v.y;
    v1 += (acc1[2] > 0.f ? acc1[2] : 0.f) * w2v.z;
    v1 += (acc1[3] > 0.f ? acc1[3] : 0.f) * w2v.w;
#pragma unroll
    for (int o = 1; o < 32; o <<= 1) {
        v0 += __shfl_xor(v0, o, 64);
        v1 += __shfl_xor(v1, o, 64);
    }
    if (cg == 0) {
        out[a0 + ap * 2]     = v0 + b2[0];
        out[a0 + ap * 2 + 1] = v1 + b2[0];
    }
}

// ---------------- launch ----------------

extern "C" void kernel_launch(void* const* d_in, const int* in_sizes, int n_in,
                              void* d_out, int out_size, void* d_ws, size_t ws_size,
                              hipStream_t stream) {
    const float* x   = (const float*)d_in[0];
    const int* ei    = (const int*)d_in[1];
    const int* asrc  = (const int*)d_in[2];
    const int* adst  = (const int*)d_in[3];
    const int* atype = (const int*)d_in[4];
    const float* gW  = (const float*)d_in[5];
    const float* gas = (const float*)d_in[6];
    const float* gad = (const float*)d_in[7];
    const float* gb  = (const float*)d_in[8];
    const float* W1  = (const float*)d_in[9];
    const float* b1  = (const float*)d_in[10];
    const float* W2  = (const float*)d_in[11];
    const float* b2  = (const float*)d_in[12];
    float* out = (float*)d_out;

    __half* z16A = (__half*)d_ws;                       // 2.56 MB
    __half* z16B = z16A + N_NODES * HID;                // 2.56 MB
    float* h3   = (float*)(z16B + N_NODES * HID);       // 5.12 MB
    float* zsA  = h3 + N_NODES * HID;
    float* zdA  = zsA + N_NODES;
    float* zsB  = zdA + N_NODES;
    float* zdB  = zsB + N_NODES;
    int* offs   = (int*)(zdB + N_NODES);
    int* csr    = offs + (N_NODES + 1);
    int* bcnt   = csr + TOT_E;
    unsigned* bpart = (unsigned*)(bcnt + P1_BLOCKS * 256);

    part1_k<<<P1_BLOCKS, 256, 0, stream>>>(ei, bpart, bcnt);
    g2_k<<<G_BLOCKS + NBKT, 256, 0, stream>>>(x, gW, gas, gad, z16A, zsA, zdA,
                                              bpart, bcnt, csr, offs);

    fuse_k<<<N_NODES / 16, 256, 0, stream>>>(z16A, zsA, zdA, offs, csr, gb,
                                             gW + 1 * HID * HID, gas + 1 * HID, gad + 1 * HID,
                                             z16B, zsB, zdB);
    fuse_k<<<N_NODES / 16, 256, 0, stream>>>(z16B, zsB, zdB, offs, csr, gb + 1 * HID,
                                             gW + 2 * HID * HID, gas + 2 * HID, gad + 2 * HID,
                                             z16A, zsA, zdA);
    agg_k<<<(N_NODES + 3) / 4, 256, 0, stream>>>(z16A, zsA, zdA, offs, csr,
                                                 gb + 2 * HID, h3);
    score_k<<<N_ACT / SC_APB, 256, 0, stream>>>(h3, asrc, adst, atype,
                                                W1, b1, W2, b2, out);
}

// Round 6
// 212.395 us; speedup vs baseline: 3.7762x; 1.0450x over previous
//
#include <hip/hip_runtime.h>
#include <hip/hip_bf16.h>
#include <hip/hip_fp16.h>

#define N_NODES 10000
#define N_EDGES 640000
#define TOT_E   (N_EDGES + N_NODES)
#define HID     128
#define NEG_SLOPE 0.2f
#define N_ACT   4096

// ---- deterministic bucket counting-sort CSR build (no global atomics) ----
#define NBKT   250
#define NPB    40
#define P1_EPB 4096
#define P1_EPT 16
#define P1_BLOCKS 159
#define SLOTP  56
#define G_BLOCKS 313   // ceil(N_NODES/32) gemm-role blocks in merged kernel
#define AGG_B  2048    // agg grid: all resident at 8 blocks/CU

__global__ __launch_bounds__(256) void part1_k(const int* __restrict__ ei,
                                               unsigned* __restrict__ bpart,
                                               int* __restrict__ bcnt) {
    __shared__ int hist[256];
    __shared__ int lofs[256];
    __shared__ int sc[256];
    __shared__ unsigned stage[P1_EPB];
    __shared__ unsigned char bkt_of[P1_EPB];
    int t = threadIdx.x;
    hist[t] = 0;
    __syncthreads();

    unsigned pk[P1_EPT];
    int bk[P1_EPT];
    int e0 = blockIdx.x * P1_EPB;
#pragma unroll
    for (int i = 0; i < P1_EPT; i++) {
        int e = e0 + i * 256 + t;
        if (e < TOT_E) {
            int src, dst;
            if (e < N_EDGES) { src = ei[e]; dst = ei[N_EDGES + e]; }
            else             { src = e - N_EDGES; dst = src; }
            pk[i] = ((unsigned)dst << 16) | (unsigned)src;
            bk[i] = dst / NPB;
            atomicAdd(&hist[bk[i]], 1);
        } else bk[i] = -1;
    }
    __syncthreads();
    int v = hist[t];
    sc[t] = v;
    __syncthreads();
    for (int o = 1; o < 256; o <<= 1) {
        int u = (t >= o) ? sc[t - o] : 0;
        __syncthreads();
        sc[t] += u;
        __syncthreads();
    }
    lofs[t] = sc[t] - v;
    bcnt[blockIdx.x * 256 + t] = v;
    hist[t] = 0;
    __syncthreads();
#pragma unroll
    for (int i = 0; i < P1_EPT; i++) {
        if (bk[i] >= 0) {
            int p = atomicAdd(&hist[bk[i]], 1);
            int slot = lofs[bk[i]] + p;
            stage[slot] = pk[i];
            bkt_of[slot] = (unsigned char)bk[i];
        }
    }
    __syncthreads();
    int nv = min(P1_EPB, TOT_E - e0);
    for (int s = t; s < nv; s += 256) {
        int b = bkt_of[s];
        bpart[b * (P1_BLOCKS * SLOTP) + blockIdx.x * SLOTP + (s - lofs[b])] = stage[s];
    }
}

// -------- per-wave edge aggregate core (R1-proven simple form) --------
__device__ __forceinline__ void agg_node(const __half2* __restrict__ z2,
                                         const float* __restrict__ zsi, float zdn,
                                         const int* __restrict__ csr, int o0, int deg,
                                         int lane, float& accx, float& accy, float& denom) {
    for (int base = 0; base < deg; base += 64) {
        int j = base + lane;
        int sreg = 0;
        float ex = 0.f;
        if (j < deg) {
            int s = csr[o0 + j];
            sreg = s;
            float e = zsi[s] + zdn;
            e = e > 0.f ? e : NEG_SLOPE * e;
            ex = __expf(e);
        }
        int cnt = min(64, deg - base);
        int q = 0;
        for (; q + 8 <= cnt; q += 8) {
#pragma unroll
            for (int u = 0; u < 8; u++) {
                int sq = __builtin_amdgcn_readlane(sreg, q + u);
                float exq = __uint_as_float(
                    __builtin_amdgcn_readlane(__float_as_uint(ex), q + u));
                denom += exq;
                float2 vf = __half22float2(z2[sq * 64]);
                accx = fmaf(exq, vf.x, accx);
                accy = fmaf(exq, vf.y, accy);
            }
        }
        for (; q < cnt; q++) {
            int sq = __builtin_amdgcn_readlane(sreg, q);
            float exq = __uint_as_float(
                __builtin_amdgcn_readlane(__float_as_uint(ex), q));
            denom += exq;
            float2 vf = __half22float2(z2[sq * 64]);
            accx = fmaf(exq, vf.x, accx);
            accy = fmaf(exq, vf.y, accy);
        }
    }
}

__device__ __forceinline__ void gload_lds16(const float* g, float* l) {
    __builtin_amdgcn_global_load_lds(
        (const __attribute__((address_space(1))) void*)g,
        (__attribute__((address_space(3))) void*)l, 16, 0, 0);
}

// -------- shared gemm body: z16 = fp16(A@W), zs, zd (one-shot LDS residency) --------
__device__ __forceinline__ void gemm_body(const float* __restrict__ A,
                                          const float* __restrict__ W,
                                          const float* __restrict__ avs,
                                          const float* __restrict__ avd,
                                          __half* __restrict__ z16,
                                          float* __restrict__ zs,
                                          float* __restrict__ zd,
                                          float* smem, int blk, int t) {
    float* As = smem;            // 16 KB
    float* Ws = smem + 32 * HID; // 64 KB
    int w = t >> 6, lane = t & 63;
    int row0 = blk * 32;
#pragma unroll
    for (int i = 0; i < 4; i++) {
        int chunk = w * 4 + i;
        long foff = (long)row0 * HID + chunk * 256;
        const float* g = ((foff + 256) <= (long)N_NODES * HID) ? (A + foff + lane * 4)
                                                               : (A + lane * 4);
        gload_lds16(g, As + chunk * 256);
    }
#pragma unroll
    for (int i = 0; i < 16; i++) {
        int chunk = w * 16 + i;
        gload_lds16(W + chunk * 256 + lane * 4, Ws + chunk * 256);
    }
    __syncthreads();

    int tx = t & 31, ty = t >> 5;
    int r0 = ty * 4;
    float acc[4][4] = {{0.f}};
#pragma unroll 4
    for (int k4 = 0; k4 < 32; k4++) {
        float ak[4][4];
#pragma unroll
        for (int r = 0; r < 4; r++) {
            float4 a4 = *(const float4*)&As[(r0 + r) * HID + k4 * 4];
            ak[r][0] = a4.x; ak[r][1] = a4.y; ak[r][2] = a4.z; ak[r][3] = a4.w;
        }
        const float* Wb = &Ws[k4 * 4 * HID + tx * 4];
#pragma unroll
        for (int kk = 0; kk < 4; kk++) {
            float4 wv = *(const float4*)&Wb[kk * HID];
#pragma unroll
            for (int r = 0; r < 4; r++) {
                acc[r][0] = fmaf(ak[r][kk], wv.x, acc[r][0]);
                acc[r][1] = fmaf(ak[r][kk], wv.y, acc[r][1]);
                acc[r][2] = fmaf(ak[r][kk], wv.z, acc[r][2]);
                acc[r][3] = fmaf(ak[r][kk], wv.w, acc[r][3]);
            }
        }
    }
    float4 asv = *(const float4*)&avs[tx * 4];
    float4 adv = *(const float4*)&avd[tx * 4];
#pragma unroll
    for (int r = 0; r < 4; r++) {
        int row = row0 + r0 + r;
        if (row < N_NODES) {
            *(__half2*)&z16[row * HID + tx * 4]     = __floats2half2_rn(acc[r][0], acc[r][1]);
            *(__half2*)&z16[row * HID + tx * 4 + 2] = __floats2half2_rn(acc[r][2], acc[r][3]);
        }
        float ps = acc[r][0] * asv.x + acc[r][1] * asv.y + acc[r][2] * asv.z + acc[r][3] * asv.w;
        float pd = acc[r][0] * adv.x + acc[r][1] * adv.y + acc[r][2] * adv.z + acc[r][3] * adv.w;
#pragma unroll
        for (int o = 1; o < 32; o <<= 1) {
            ps += __shfl_xor(ps, o, 64);
            pd += __shfl_xor(pd, o, 64);
        }
        if (tx == 0 && row < N_NODES) { zs[row] = ps; zd[row] = pd; }
    }
}

// -------- merged: gemm0 (blocks < G_BLOCKS)  ||  part2 CSR finalize (rest) --------
__global__ __launch_bounds__(256) void g2_k(const float* __restrict__ A,
                                            const float* __restrict__ W,
                                            const float* __restrict__ avs,
                                            const float* __restrict__ avd,
                                            __half* __restrict__ z16,
                                            float* __restrict__ zs,
                                            float* __restrict__ zd,
                                            const unsigned* __restrict__ bpart,
                                            const int* __restrict__ bcnt,
                                            int* __restrict__ csr,
                                            int* __restrict__ offs) {
    __shared__ float smem[20480];   // 80 KB, carved per role
    int t = threadIdx.x;

    if (blockIdx.x < G_BLOCKS) {
        gemm_body(A, W, avs, avd, z16, zs, zd, smem, blockIdx.x, t);
    } else {
        // ---------------- part2 role: CSR finalize ----------------
        int b = blockIdx.x - G_BLOCKS;
        unsigned* ebuf = (unsigned*)smem;          // 16 KB
        int* sc    = (int*)(smem + 4096);          // 1 KB
        int* Ls    = sc + 256;                     // 1 KB
        int* nhist = Ls + 256;                     // 160 B
        __shared__ int bstart_s, cnt_s;

        int tot = 0;
        if (t < NBKT) {
            int t0 = 0, t1 = 0, t2 = 0, t3 = 0;
            int blk = 0;
            for (; blk + 4 <= P1_BLOCKS; blk += 4) {
                t0 += bcnt[(blk + 0) * 256 + t];
                t1 += bcnt[(blk + 1) * 256 + t];
                t2 += bcnt[(blk + 2) * 256 + t];
                t3 += bcnt[(blk + 3) * 256 + t];
            }
            for (; blk < P1_BLOCKS; blk++) t0 += bcnt[blk * 256 + t];
            tot = t0 + t1 + t2 + t3;
        }
        sc[t] = tot;
        __syncthreads();
        for (int o = 1; o < 256; o <<= 1) {
            int u = (t >= o) ? sc[t - o] : 0;
            __syncthreads();
            sc[t] += u;
            __syncthreads();
        }
        if (t == b) { bstart_s = sc[t] - tot; cnt_s = tot; }
        if (b == 0 && t == 255) offs[N_NODES] = sc[255];
        __syncthreads();

        int L = (t < P1_BLOCKS) ? bcnt[t * 256 + b] : 0;
        Ls[t] = L;
        sc[t] = L;
        __syncthreads();
        for (int o = 1; o < 256; o <<= 1) {
            int u = (t >= o) ? sc[t - o] : 0;
            __syncthreads();
            sc[t] += u;
            __syncthreads();
        }
        if (t < NPB) nhist[t] = 0;
        {
            int wv = t >> 6, lane = t & 63;
            const unsigned* bbase = bpart + b * (P1_BLOCKS * SLOTP);
            for (int r = wv; r < P1_BLOCKS; r += 4) {
                int Lr = Ls[r];
                if (lane < Lr) ebuf[(sc[r] - Lr) + lane] = bbase[r * SLOTP + lane];
            }
        }
        __syncthreads();

        int cnt = cnt_s;
        int n0 = b * NPB;
        for (int i = t; i < cnt; i += 256) atomicAdd(&nhist[(ebuf[i] >> 16) - n0], 1);
        __syncthreads();
        if (t < 64) {
            int v2 = (t < NPB) ? nhist[t] : 0;
            int s2 = v2;
            for (int o = 1; o < 64; o <<= 1) {
                int u = __shfl_up(s2, o, 64);
                if (t >= o) s2 += u;
            }
            if (t < NPB) {
                int ofs = bstart_s + s2 - v2;
                nhist[t] = ofs;
                offs[n0 + t] = ofs;
            }
        }
        __syncthreads();
        for (int i = t; i < cnt; i += 256) {
            unsigned pk = ebuf[i];
            int p = atomicAdd(&nhist[(pk >> 16) - n0], 1);
            csr[p] = pk & 0xFFFF;
        }
    }
}

// -------- standalone layer GEMM: h(f32) @ W -> z16, zs, zd --------
__global__ __launch_bounds__(256) void gemmh_k(const float* __restrict__ A,
                                               const float* __restrict__ W,
                                               const float* __restrict__ avs,
                                               const float* __restrict__ avd,
                                               __half* __restrict__ z16,
                                               float* __restrict__ zs,
                                               float* __restrict__ zd) {
    __shared__ float smem[20480];   // 80 KB
    gemm_body(A, W, avs, avd, z16, zs, zd, smem, blockIdx.x, threadIdx.x);
}

// -------- aggregate layer: softmax-weighted neighbor sum -> h (f32) --------
// 0 LDS, VGPR capped at 64 via (256,8): 8 waves/SIMD = 32 waves/CU of
// latency hiding for the random-row gather. Grid-stride, all blocks resident.
__global__ __launch_bounds__(256, 8) void agg_k(const __half* __restrict__ z16,
                                                const float* __restrict__ zs,
                                                const float* __restrict__ zd,
                                                const int* __restrict__ offs,
                                                const int* __restrict__ csr,
                                                const float* __restrict__ b,
                                                float* __restrict__ hout) {
    int t = threadIdx.x;
    int w = t >> 6, lane = t & 63;
    const __half2* z2 = (const __half2*)z16 + lane;
    float2 bv = *(const float2*)&b[2 * lane];
    for (int n = blockIdx.x * 4 + w; n < N_NODES; n += AGG_B * 4) {
        int o0 = offs[n];
        int deg = offs[n + 1] - o0;
        float zdn = zd[n];
        float accx = 0.f, accy = 0.f, denom = 0.f;
        agg_node(z2, zs, zdn, csr, o0, deg, lane, accx, accy, denom);
        float inv = 1.0f / denom;
        float vx = accx * inv + bv.x;
        float vy = accy * inv + bv.y;
        float2 o;
        o.x = vx > 0.f ? vx : 0.f;
        o.y = vy > 0.f ? vy : 0.f;
        *(float2*)&hout[n * HID + 2 * lane] = o;
    }
}

// -------- action scoring: tiled GEMM, 16 actions/block × 256 blocks, dbuf W1 --------

#define SC_APB 16

__global__ __launch_bounds__(256) void score_k(const float* __restrict__ h,
                                               const int* __restrict__ asrc,
                                               const int* __restrict__ adst,
                                               const int* __restrict__ atype,
                                               const float* __restrict__ W1,
                                               const float* __restrict__ b1,
                                               const float* __restrict__ W2,
                                               const float* __restrict__ b2,
                                               float* __restrict__ out) {
    __shared__ float featT[257][SC_APB + 1];   // [k][action], padded: 17.5 KB
    __shared__ float Wc[2][32 * HID];          // 32 KB
    int t = threadIdx.x;
    int a0 = blockIdx.x * SC_APB;

    float4 wreg[4];
    {
        const float4* Wg = (const float4*)W1;
#pragma unroll
        for (int i = 0; i < 4; i++) wreg[i] = Wg[t + 256 * i];
    }
    for (int idx = t; idx < SC_APB * 128; idx += 256) {
        int a = idx >> 7, c = idx & 127;
        featT[c][a]       = h[asrc[a0 + a] * HID + c];
        featT[128 + c][a] = h[adst[a0 + a] * HID + c];
    }
    if (t < SC_APB) featT[256][t] = (float)atype[a0 + t];

    int cg = t & 31, ap = t >> 5;
    float4 bv = *(const float4*)&b1[cg * 4];
    float acc0[4] = {bv.x, bv.y, bv.z, bv.w};
    float acc1[4] = {bv.x, bv.y, bv.z, bv.w};

    for (int c = 0; c < 8; c++) {
        float4* dstb = (float4*)Wc[c & 1];
#pragma unroll
        for (int i = 0; i < 4; i++) dstb[t + 256 * i] = wreg[i];
        __syncthreads();
        if (c + 1 < 8) {
            const float4* Wg = (const float4*)(W1 + (c + 1) * 32 * HID);
#pragma unroll
            for (int i = 0; i < 4; i++) wreg[i] = Wg[t + 256 * i];
        }
        const float* Wb = Wc[c & 1];
        const float* fT = &featT[c * 32][0];
#pragma unroll 8
        for (int kk = 0; kk < 32; kk++) {
            float4 wv = *(const float4*)&Wb[kk * HID + cg * 4];
            float f0 = fT[kk * (SC_APB + 1) + ap * 2];
            float f1 = fT[kk * (SC_APB + 1) + ap * 2 + 1];
            acc0[0] = fmaf(f0, wv.x, acc0[0]);
            acc0[1] = fmaf(f0, wv.y, acc0[1]);
            acc0[2] = fmaf(f0, wv.z, acc0[2]);
            acc0[3] = fmaf(f0, wv.w, acc0[3]);
            acc1[0] = fmaf(f1, wv.x, acc1[0]);
            acc1[1] = fmaf(f1, wv.y, acc1[1]);
            acc1[2] = fmaf(f1, wv.z, acc1[2]);
            acc1[3] = fmaf(f1, wv.w, acc1[3]);
        }
    }
    {
        float4 wv = *(const float4*)&W1[256 * HID + cg * 4];
        float f0 = featT[256][ap * 2];
        float f1 = featT[256][ap * 2 + 1];
        acc0[0] = fmaf(f0, wv.x, acc0[0]); acc0[1] = fmaf(f0, wv.y, acc0[1]);
        acc0[2] = fmaf(f0, wv.z, acc0[2]); acc0[3] = fmaf(f0, wv.w, acc0[3]);
        acc1[0] = fmaf(f1, wv.x, acc1[0]); acc1[1] = fmaf(f1, wv.y, acc1[1]);
        acc1[2] = fmaf(f1, wv.z, acc1[2]); acc1[3] = fmaf(f1, wv.w, acc1[3]);
    }
    float4 w2v = *(const float4*)&W2[cg * 4];
    float v0 = 0.f, v1 = 0.f;
    v0 += (acc0[0] > 0.f ? acc0[0] : 0.f) * w2v.x;
    v0 += (acc0[1] > 0.f ? acc0[1] : 0.f) * w2v.y;
    v0 += (acc0[2] > 0.f ? acc0[2] : 0.f) * w2v.z;
    v0 += (acc0[3] > 0.f ? acc0[3] : 0.f) * w2v.w;
    v1 += (acc1[0] > 0.f ? acc1[0] : 0.f) * w2v.x;
    v1 += (acc1[1] > 0.f ? acc1[1] : 0.f) * w2v.y;
    v1 += (acc1[2] > 0.f ? acc1[2] : 0.f) * w2v.z;
    v1 += (acc1[3] > 0.f ? acc1[3] : 0.f) * w2v.w;
#pragma unroll
    for (int o = 1; o < 32; o <<= 1) {
        v0 += __shfl_xor(v0, o, 64);
        v1 += __shfl_xor(v1, o, 64);
    }
    if (cg == 0) {
        out[a0 + ap * 2]     = v0 + b2[0];
        out[a0 + ap * 2 + 1] = v1 + b2[0];
    }
}

// ---------------- launch ----------------

extern "C" void kernel_launch(void* const* d_in, const int* in_sizes, int n_in,
                              void* d_out, int out_size, void* d_ws, size_t ws_size,
                              hipStream_t stream) {
    const float* x   = (const float*)d_in[0];
    const int* ei    = (const int*)d_in[1];
    const int* asrc  = (const int*)d_in[2];
    const int* adst  = (const int*)d_in[3];
    const int* atype = (const int*)d_in[4];
    const float* gW  = (const float*)d_in[5];
    const float* gas = (const float*)d_in[6];
    const float* gad = (const float*)d_in[7];
    const float* gb  = (const float*)d_in[8];
    const float* W1  = (const float*)d_in[9];
    const float* b1  = (const float*)d_in[10];
    const float* W2  = (const float*)d_in[11];
    const float* b2  = (const float*)d_in[12];
    float* out = (float*)d_out;

    __half* z16A = (__half*)d_ws;                       // 2.56 MB
    __half* z16B = z16A + N_NODES * HID;                // 2.56 MB
    float* H    = (float*)(z16B + N_NODES * HID);       // 5.12 MB (shared h buffer)
    float* zsA  = H + N_NODES * HID;
    float* zdA  = zsA + N_NODES;
    float* zsB  = zdA + N_NODES;
    float* zdB  = zsB + N_NODES;
    int* offs   = (int*)(zdB + N_NODES);
    int* csr    = offs + (N_NODES + 1);
    int* bcnt   = csr + TOT_E;
    unsigned* bpart = (unsigned*)(bcnt + P1_BLOCKS * 256);

    part1_k<<<P1_BLOCKS, 256, 0, stream>>>(ei, bpart, bcnt);
    g2_k<<<G_BLOCKS + NBKT, 256, 0, stream>>>(x, gW, gas, gad, z16A, zsA, zdA,
                                              bpart, bcnt, csr, offs);

    // layer 1: agg -> H -> gemm -> z16B
    agg_k<<<AGG_B, 256, 0, stream>>>(z16A, zsA, zdA, offs, csr, gb, H);
    gemmh_k<<<G_BLOCKS, 256, 0, stream>>>(H, gW + 1 * HID * HID, gas + 1 * HID,
                                          gad + 1 * HID, z16B, zsB, zdB);
    // layer 2: agg -> H -> gemm -> z16A
    agg_k<<<AGG_B, 256, 0, stream>>>(z16B, zsB, zdB, offs, csr, gb + 1 * HID, H);
    gemmh_k<<<G_BLOCKS, 256, 0, stream>>>(H, gW + 2 * HID * HID, gas + 2 * HID,
                                          gad + 2 * HID, z16A, zsA, zdA);
    // layer 3: agg -> H (final node embeddings)
    agg_k<<<AGG_B, 256, 0, stream>>>(z16A, zsA, zdA, offs, csr, gb + 2 * HID, H);

    score_k<<<N_ACT / SC_APB, 256, 0, stream>>>(H, asrc, adst, atype,
                                                W1, b1, W2, b2, out);
}

// Round 7
// 207.070 us; speedup vs baseline: 3.8734x; 1.0257x over previous
//
#include <hip/hip_runtime.h>
#include <hip/hip_bf16.h>
#include <hip/hip_fp16.h>

#define N_NODES 10000
#define N_EDGES 640000
#define TOT_E   (N_EDGES + N_NODES)
#define HID     128
#define NEG_SLOPE 0.2f
#define N_ACT   4096

// ---- deterministic bucket counting-sort CSR build (no global atomics) ----
#define NBKT   250
#define NPB    40
#define P1_EPB 4096
#define P1_EPT 16
#define P1_BLOCKS 159
#define SLOTP  56
#define G_BLOCKS 313   // ceil(N_NODES/32) gemm-role blocks in merged kernel
#define AGG_B  2048    // agg grid: all resident at 8 blocks/CU

__global__ __launch_bounds__(256) void part1_k(const int* __restrict__ ei,
                                               unsigned* __restrict__ bpart,
                                               int* __restrict__ bcnt) {
    __shared__ int hist[256];
    __shared__ int lofs[256];
    __shared__ int sc[256];
    __shared__ unsigned stage[P1_EPB];
    __shared__ unsigned char bkt_of[P1_EPB];
    int t = threadIdx.x;
    hist[t] = 0;
    __syncthreads();

    unsigned pk[P1_EPT];
    int bk[P1_EPT];
    int e0 = blockIdx.x * P1_EPB;
#pragma unroll
    for (int i = 0; i < P1_EPT; i++) {
        int e = e0 + i * 256 + t;
        if (e < TOT_E) {
            int src, dst;
            if (e < N_EDGES) { src = ei[e]; dst = ei[N_EDGES + e]; }
            else             { src = e - N_EDGES; dst = src; }
            pk[i] = ((unsigned)dst << 16) | (unsigned)src;
            bk[i] = dst / NPB;
            atomicAdd(&hist[bk[i]], 1);
        } else bk[i] = -1;
    }
    __syncthreads();
    int v = hist[t];
    sc[t] = v;
    __syncthreads();
    for (int o = 1; o < 256; o <<= 1) {
        int u = (t >= o) ? sc[t - o] : 0;
        __syncthreads();
        sc[t] += u;
        __syncthreads();
    }
    lofs[t] = sc[t] - v;
    bcnt[blockIdx.x * 256 + t] = v;
    hist[t] = 0;
    __syncthreads();
#pragma unroll
    for (int i = 0; i < P1_EPT; i++) {
        if (bk[i] >= 0) {
            int p = atomicAdd(&hist[bk[i]], 1);
            int slot = lofs[bk[i]] + p;
            stage[slot] = pk[i];
            bkt_of[slot] = (unsigned char)bk[i];
        }
    }
    __syncthreads();
    int nv = min(P1_EPB, TOT_E - e0);
    for (int s = t; s < nv; s += 256) {
        int b = bkt_of[s];
        bpart[b * (P1_BLOCKS * SLOTP) + blockIdx.x * SLOTP + (s - lofs[b])] = stage[s];
    }
}

__device__ __forceinline__ void gload_lds16(const float* g, float* l) {
    __builtin_amdgcn_global_load_lds(
        (const __attribute__((address_space(1))) void*)g,
        (__attribute__((address_space(3))) void*)l, 16, 0, 0);
}

// -------- shared gemm body: z16 = fp16(A@W), zs, zd (one-shot LDS residency) --------
__device__ __forceinline__ void gemm_body(const float* __restrict__ A,
                                          const float* __restrict__ W,
                                          const float* __restrict__ avs,
                                          const float* __restrict__ avd,
                                          __half* __restrict__ z16,
                                          float* __restrict__ zs,
                                          float* __restrict__ zd,
                                          float* smem, int blk, int t) {
    float* As = smem;            // 16 KB
    float* Ws = smem + 32 * HID; // 64 KB
    int w = t >> 6, lane = t & 63;
    int row0 = blk * 32;
#pragma unroll
    for (int i = 0; i < 4; i++) {
        int chunk = w * 4 + i;
        long foff = (long)row0 * HID + chunk * 256;
        const float* g = ((foff + 256) <= (long)N_NODES * HID) ? (A + foff + lane * 4)
                                                               : (A + lane * 4);
        gload_lds16(g, As + chunk * 256);
    }
#pragma unroll
    for (int i = 0; i < 16; i++) {
        int chunk = w * 16 + i;
        gload_lds16(W + chunk * 256 + lane * 4, Ws + chunk * 256);
    }
    __syncthreads();

    int tx = t & 31, ty = t >> 5;
    int r0 = ty * 4;
    float acc[4][4] = {{0.f}};
#pragma unroll 4
    for (int k4 = 0; k4 < 32; k4++) {
        float ak[4][4];
#pragma unroll
        for (int r = 0; r < 4; r++) {
            float4 a4 = *(const float4*)&As[(r0 + r) * HID + k4 * 4];
            ak[r][0] = a4.x; ak[r][1] = a4.y; ak[r][2] = a4.z; ak[r][3] = a4.w;
        }
        const float* Wb = &Ws[k4 * 4 * HID + tx * 4];
#pragma unroll
        for (int kk = 0; kk < 4; kk++) {
            float4 wv = *(const float4*)&Wb[kk * HID];
#pragma unroll
            for (int r = 0; r < 4; r++) {
                acc[r][0] = fmaf(ak[r][kk], wv.x, acc[r][0]);
                acc[r][1] = fmaf(ak[r][kk], wv.y, acc[r][1]);
                acc[r][2] = fmaf(ak[r][kk], wv.z, acc[r][2]);
                acc[r][3] = fmaf(ak[r][kk], wv.w, acc[r][3]);
            }
        }
    }
    float4 asv = *(const float4*)&avs[tx * 4];
    float4 adv = *(const float4*)&avd[tx * 4];
#pragma unroll
    for (int r = 0; r < 4; r++) {
        int row = row0 + r0 + r;
        if (row < N_NODES) {
            *(__half2*)&z16[row * HID + tx * 4]     = __floats2half2_rn(acc[r][0], acc[r][1]);
            *(__half2*)&z16[row * HID + tx * 4 + 2] = __floats2half2_rn(acc[r][2], acc[r][3]);
        }
        float ps = acc[r][0] * asv.x + acc[r][1] * asv.y + acc[r][2] * asv.z + acc[r][3] * asv.w;
        float pd = acc[r][0] * adv.x + acc[r][1] * adv.y + acc[r][2] * adv.z + acc[r][3] * adv.w;
#pragma unroll
        for (int o = 1; o < 32; o <<= 1) {
            ps += __shfl_xor(ps, o, 64);
            pd += __shfl_xor(pd, o, 64);
        }
        if (tx == 0 && row < N_NODES) { zs[row] = ps; zd[row] = pd; }
    }
}

// -------- merged: gemm0 (blocks < G_BLOCKS)  ||  part2 CSR finalize (rest) --------
__global__ __launch_bounds__(256) void g2_k(const float* __restrict__ A,
                                            const float* __restrict__ W,
                                            const float* __restrict__ avs,
                                            const float* __restrict__ avd,
                                            __half* __restrict__ z16,
                                            float* __restrict__ zs,
                                            float* __restrict__ zd,
                                            const unsigned* __restrict__ bpart,
                                            const int* __restrict__ bcnt,
                                            int* __restrict__ csr,
                                            int* __restrict__ offs) {
    __shared__ float smem[20480];   // 80 KB, carved per role
    int t = threadIdx.x;

    if (blockIdx.x < G_BLOCKS) {
        gemm_body(A, W, avs, avd, z16, zs, zd, smem, blockIdx.x, t);
    } else {
        // ---------------- part2 role: CSR finalize ----------------
        int b = blockIdx.x - G_BLOCKS;
        unsigned* ebuf = (unsigned*)smem;          // 16 KB
        int* sc    = (int*)(smem + 4096);          // 1 KB
        int* Ls    = sc + 256;                     // 1 KB
        int* nhist = Ls + 256;                     // 160 B
        __shared__ int bstart_s, cnt_s;

        int tot = 0;
        if (t < NBKT) {
            int t0 = 0, t1 = 0, t2 = 0, t3 = 0;
            int blk = 0;
            for (; blk + 4 <= P1_BLOCKS; blk += 4) {
                t0 += bcnt[(blk + 0) * 256 + t];
                t1 += bcnt[(blk + 1) * 256 + t];
                t2 += bcnt[(blk + 2) * 256 + t];
                t3 += bcnt[(blk + 3) * 256 + t];
            }
            for (; blk < P1_BLOCKS; blk++) t0 += bcnt[blk * 256 + t];
            tot = t0 + t1 + t2 + t3;
        }
        sc[t] = tot;
        __syncthreads();
        for (int o = 1; o < 256; o <<= 1) {
            int u = (t >= o) ? sc[t - o] : 0;
            __syncthreads();
            sc[t] += u;
            __syncthreads();
        }
        if (t == b) { bstart_s = sc[t] - tot; cnt_s = tot; }
        if (b == 0 && t == 255) offs[N_NODES] = sc[255];
        __syncthreads();

        int L = (t < P1_BLOCKS) ? bcnt[t * 256 + b] : 0;
        Ls[t] = L;
        sc[t] = L;
        __syncthreads();
        for (int o = 1; o < 256; o <<= 1) {
            int u = (t >= o) ? sc[t - o] : 0;
            __syncthreads();
            sc[t] += u;
            __syncthreads();
        }
        if (t < NPB) nhist[t] = 0;
        {
            int wv = t >> 6, lane = t & 63;
            const unsigned* bbase = bpart + b * (P1_BLOCKS * SLOTP);
            for (int r = wv; r < P1_BLOCKS; r += 4) {
                int Lr = Ls[r];
                if (lane < Lr) ebuf[(sc[r] - Lr) + lane] = bbase[r * SLOTP + lane];
            }
        }
        __syncthreads();

        int cnt = cnt_s;
        int n0 = b * NPB;
        for (int i = t; i < cnt; i += 256) atomicAdd(&nhist[(ebuf[i] >> 16) - n0], 1);
        __syncthreads();
        if (t < 64) {
            int v2 = (t < NPB) ? nhist[t] : 0;
            int s2 = v2;
            for (int o = 1; o < 64; o <<= 1) {
                int u = __shfl_up(s2, o, 64);
                if (t >= o) s2 += u;
            }
            if (t < NPB) {
                int ofs = bstart_s + s2 - v2;
                nhist[t] = ofs;
                offs[n0 + t] = ofs;
            }
        }
        __syncthreads();
        for (int i = t; i < cnt; i += 256) {
            unsigned pk = ebuf[i];
            int p = atomicAdd(&nhist[(pk >> 16) - n0], 1);
            csr[p] = pk & 0xFFFF;
        }
    }
}

// -------- standalone layer GEMM: h(f32) @ W -> z16, zs, zd --------
__global__ __launch_bounds__(256) void gemmh_k(const float* __restrict__ A,
                                               const float* __restrict__ W,
                                               const float* __restrict__ avs,
                                               const float* __restrict__ avd,
                                               __half* __restrict__ z16,
                                               float* __restrict__ zs,
                                               float* __restrict__ zd) {
    __shared__ float smem[20480];   // 80 KB
    gemm_body(A, W, avs, avd, z16, zs, zd, smem, blockIdx.x, threadIdx.x);
}

// -------- aggregate layer: softmax-weighted neighbor sum -> h (f32) --------
// Quarter-wave edge vectorization: 4 groups of 16 lanes; group g handles
// edge q+g, each lane loads 16 B (dwordx4) of the row -> 4x fewer VMEM
// instructions, no readlane->SGPR serialization. acc = 8 floats/lane
// (feature slice l16*8..+7), cross-group combine via 2 shfl_xor at node end.
// 0 LDS, (256,8): 32 waves/CU of latency hiding.
__global__ __launch_bounds__(256, 8) void agg_k(const __half* __restrict__ z16,
                                                const float* __restrict__ zs,
                                                const float* __restrict__ zd,
                                                const int* __restrict__ offs,
                                                const int* __restrict__ csr,
                                                const float* __restrict__ b,
                                                float* __restrict__ hout) {
    int t = threadIdx.x;
    int w = t >> 6, lane = t & 63;
    int grp = lane >> 4, l16 = lane & 15;
    const char* zb = (const char*)z16;
    unsigned loff = l16 * 16;
    for (int n = blockIdx.x * 4 + w; n < N_NODES; n += AGG_B * 4) {
        int o0 = offs[n];
        int deg = offs[n + 1] - o0;
        float zdn = zd[n];
        float acc[8] = {0.f, 0.f, 0.f, 0.f, 0.f, 0.f, 0.f, 0.f};
        float denomv = 0.f;
        for (int base = 0; base < deg; base += 64) {
            int j = base + lane;
            int sreg = 0;
            float ex = 0.f;
            if (j < deg) {
                int s = csr[o0 + j];
                sreg = s;
                float e = zs[s] + zdn;
                e = e > 0.f ? e : NEG_SLOPE * e;
                ex = __expf(e);
            }
            int cnt = min(64, deg - base);
            for (int q = 0; q < cnt; q += 4) {
                int idx = q + grp;
                int sqv = __shfl(sreg, idx, 64);       // bpermute: per-lane src row
                float exv = __shfl(ex, idx, 64);       // (ex=0 for tail lanes -> no-op)
                float4 rv = *(const float4*)(zb + (unsigned)sqv * 256u + loff);
                denomv += exv;
                const __half2* hp = (const __half2*)&rv;
#pragma unroll
                for (int u = 0; u < 4; u++) {
                    float2 f = __half22float2(hp[u]);
                    acc[2 * u]     = fmaf(exv, f.x, acc[2 * u]);
                    acc[2 * u + 1] = fmaf(exv, f.y, acc[2 * u + 1]);
                }
            }
        }
        // combine the 4 edge-groups (xor bits 4,5 of lane)
#pragma unroll
        for (int u = 0; u < 8; u++) {
            acc[u] += __shfl_xor(acc[u], 16, 64);
            acc[u] += __shfl_xor(acc[u], 32, 64);
        }
        denomv += __shfl_xor(denomv, 16, 64);
        denomv += __shfl_xor(denomv, 32, 64);
        if (lane < 16) {
            float inv = 1.0f / denomv;
            float4 b0 = *(const float4*)&b[l16 * 8];
            float4 b1 = *(const float4*)&b[l16 * 8 + 4];
            float4 o0v, o1v;
            o0v.x = fmaxf(fmaf(acc[0], inv, b0.x), 0.f);
            o0v.y = fmaxf(fmaf(acc[1], inv, b0.y), 0.f);
            o0v.z = fmaxf(fmaf(acc[2], inv, b0.z), 0.f);
            o0v.w = fmaxf(fmaf(acc[3], inv, b0.w), 0.f);
            o1v.x = fmaxf(fmaf(acc[4], inv, b1.x), 0.f);
            o1v.y = fmaxf(fmaf(acc[5], inv, b1.y), 0.f);
            o1v.z = fmaxf(fmaf(acc[6], inv, b1.z), 0.f);
            o1v.w = fmaxf(fmaf(acc[7], inv, b1.w), 0.f);
            *(float4*)&hout[(long)n * HID + l16 * 8]     = o0v;
            *(float4*)&hout[(long)n * HID + l16 * 8 + 4] = o1v;
        }
    }
}

// -------- action scoring: tiled GEMM, 16 actions/block × 256 blocks, dbuf W1 --------

#define SC_APB 16

__global__ __launch_bounds__(256) void score_k(const float* __restrict__ h,
                                               const int* __restrict__ asrc,
                                               const int* __restrict__ adst,
                                               const int* __restrict__ atype,
                                               const float* __restrict__ W1,
                                               const float* __restrict__ b1,
                                               const float* __restrict__ W2,
                                               const float* __restrict__ b2,
                                               float* __restrict__ out) {
    __shared__ float featT[257][SC_APB + 1];   // [k][action], padded: 17.5 KB
    __shared__ float Wc[2][32 * HID];          // 32 KB
    int t = threadIdx.x;
    int a0 = blockIdx.x * SC_APB;

    float4 wreg[4];
    {
        const float4* Wg = (const float4*)W1;
#pragma unroll
        for (int i = 0; i < 4; i++) wreg[i] = Wg[t + 256 * i];
    }
    for (int idx = t; idx < SC_APB * 128; idx += 256) {
        int a = idx >> 7, c = idx & 127;
        featT[c][a]       = h[asrc[a0 + a] * HID + c];
        featT[128 + c][a] = h[adst[a0 + a] * HID + c];
    }
    if (t < SC_APB) featT[256][t] = (float)atype[a0 + t];

    int cg = t & 31, ap = t >> 5;
    float4 bv = *(const float4*)&b1[cg * 4];
    float acc0[4] = {bv.x, bv.y, bv.z, bv.w};
    float acc1[4] = {bv.x, bv.y, bv.z, bv.w};

    for (int c = 0; c < 8; c++) {
        float4* dstb = (float4*)Wc[c & 1];
#pragma unroll
        for (int i = 0; i < 4; i++) dstb[t + 256 * i] = wreg[i];
        __syncthreads();
        if (c + 1 < 8) {
            const float4* Wg = (const float4*)(W1 + (c + 1) * 32 * HID);
#pragma unroll
            for (int i = 0; i < 4; i++) wreg[i] = Wg[t + 256 * i];
        }
        const float* Wb = Wc[c & 1];
        const float* fT = &featT[c * 32][0];
#pragma unroll 8
        for (int kk = 0; kk < 32; kk++) {
            float4 wv = *(const float4*)&Wb[kk * HID + cg * 4];
            float f0 = fT[kk * (SC_APB + 1) + ap * 2];
            float f1 = fT[kk * (SC_APB + 1) + ap * 2 + 1];
            acc0[0] = fmaf(f0, wv.x, acc0[0]);
            acc0[1] = fmaf(f0, wv.y, acc0[1]);
            acc0[2] = fmaf(f0, wv.z, acc0[2]);
            acc0[3] = fmaf(f0, wv.w, acc0[3]);
            acc1[0] = fmaf(f1, wv.x, acc1[0]);
            acc1[1] = fmaf(f1, wv.y, acc1[1]);
            acc1[2] = fmaf(f1, wv.z, acc1[2]);
            acc1[3] = fmaf(f1, wv.w, acc1[3]);
        }
    }
    {
        float4 wv = *(const float4*)&W1[256 * HID + cg * 4];
        float f0 = featT[256][ap * 2];
        float f1 = featT[256][ap * 2 + 1];
        acc0[0] = fmaf(f0, wv.x, acc0[0]); acc0[1] = fmaf(f0, wv.y, acc0[1]);
        acc0[2] = fmaf(f0, wv.z, acc0[2]); acc0[3] = fmaf(f0, wv.w, acc0[3]);
        acc1[0] = fmaf(f1, wv.x, acc1[0]); acc1[1] = fmaf(f1, wv.y, acc1[1]);
        acc1[2] = fmaf(f1, wv.z, acc1[2]); acc1[3] = fmaf(f1, wv.w, acc1[3]);
    }
    float4 w2v = *(const float4*)&W2[cg * 4];
    float v0 = 0.f, v1 = 0.f;
    v0 += (acc0[0] > 0.f ? acc0[0] : 0.f) * w2v.x;
    v0 += (acc0[1] > 0.f ? acc0[1] : 0.f) * w2v.y;
    v0 += (acc0[2] > 0.f ? acc0[2] : 0.f) * w2v.z;
    v0 += (acc0[3] > 0.f ? acc0[3] : 0.f) * w2v.w;
    v1 += (acc1[0] > 0.f ? acc1[0] : 0.f) * w2v.x;
    v1 += (acc1[1] > 0.f ? acc1[1] : 0.f) * w2v.y;
    v1 += (acc1[2] > 0.f ? acc1[2] : 0.f) * w2v.z;
    v1 += (acc1[3] > 0.f ? acc1[3] : 0.f) * w2v.w;
#pragma unroll
    for (int o = 1; o < 32; o <<= 1) {
        v0 += __shfl_xor(v0, o, 64);
        v1 += __shfl_xor(v1, o, 64);
    }
    if (cg == 0) {
        out[a0 + ap * 2]     = v0 + b2[0];
        out[a0 + ap * 2 + 1] = v1 + b2[0];
    }
}

// ---------------- launch ----------------

extern "C" void kernel_launch(void* const* d_in, const int* in_sizes, int n_in,
                              void* d_out, int out_size, void* d_ws, size_t ws_size,
                              hipStream_t stream) {
    const float* x   = (const float*)d_in[0];
    const int* ei    = (const int*)d_in[1];
    const int* asrc  = (const int*)d_in[2];
    const int* adst  = (const int*)d_in[3];
    const int* atype = (const int*)d_in[4];
    const float* gW  = (const float*)d_in[5];
    const float* gas = (const float*)d_in[6];
    const float* gad = (const float*)d_in[7];
    const float* gb  = (const float*)d_in[8];
    const float* W1  = (const float*)d_in[9];
    const float* b1  = (const float*)d_in[10];
    const float* W2  = (const float*)d_in[11];
    const float* b2  = (const float*)d_in[12];
    float* out = (float*)d_out;

    __half* z16A = (__half*)d_ws;                       // 2.56 MB
    __half* z16B = z16A + N_NODES * HID;                // 2.56 MB
    float* H    = (float*)(z16B + N_NODES * HID);       // 5.12 MB (shared h buffer)
    float* zsA  = H + N_NODES * HID;
    float* zdA  = zsA + N_NODES;
    float* zsB  = zdA + N_NODES;
    float* zdB  = zsB + N_NODES;
    int* offs   = (int*)(zdB + N_NODES);
    int* csr    = offs + (N_NODES + 1);
    int* bcnt   = csr + TOT_E;
    unsigned* bpart = (unsigned*)(bcnt + P1_BLOCKS * 256);

    part1_k<<<P1_BLOCKS, 256, 0, stream>>>(ei, bpart, bcnt);
    g2_k<<<G_BLOCKS + NBKT, 256, 0, stream>>>(x, gW, gas, gad, z16A, zsA, zdA,
                                              bpart, bcnt, csr, offs);

    // layer 1: agg -> H -> gemm -> z16B
    agg_k<<<AGG_B, 256, 0, stream>>>(z16A, zsA, zdA, offs, csr, gb, H);
    gemmh_k<<<G_BLOCKS, 256, 0, stream>>>(H, gW + 1 * HID * HID, gas + 1 * HID,
                                          gad + 1 * HID, z16B, zsB, zdB);
    // layer 2: agg -> H -> gemm -> z16A
    agg_k<<<AGG_B, 256, 0, stream>>>(z16B, zsB, zdB, offs, csr, gb + 1 * HID, H);
    gemmh_k<<<G_BLOCKS, 256, 0, stream>>>(H, gW + 2 * HID * HID, gas + 2 * HID,
                                          gad + 2 * HID, z16A, zsA, zdA);
    // layer 3: agg -> H (final node embeddings)
    agg_k<<<AGG_B, 256, 0, stream>>>(z16A, zsA, zdA, offs, csr, gb + 2 * HID, H);

    score_k<<<N_ACT / SC_APB, 256, 0, stream>>>(H, asrc, adst, atype,
                                                W1, b1, W2, b2, out);
}